// Round 1
// baseline (1288.620 us; speedup 1.0000x reference)
//
#include <hip/hip_runtime.h>
#include <cstdint>
#include <cstddef>

#define BS 1024            // NMS block size (16 waves)
#define MAXDET 300
#define IOU_THR 0.6f
#define SCORE_THR 0.05f

__device__ __forceinline__ void combineMax(float& bs, int& bi, float os, int oi) {
    if (os > bs || (os == bs && oi < bi)) { bs = os; bi = oi; }
}

// One block per (image b, class c). Lazy greedy NMS:
//   scores held in registers (NPT per thread); repeatedly argmax over
//   unexamined candidates, test against kept list (LDS, <=300), keep/discard.
// Equivalent to the reference's eager greedy NMS (sorted-order processing).
template<int NPT>
__global__ __launch_bounds__(BS) void nms_kernel(
    const float* __restrict__ boxes, const float* __restrict__ cls,
    const float* __restrict__ cent, int B, int N, int C,
    int* __restrict__ keptIdx, float* __restrict__ keptScore, int* __restrict__ keptCnt)
{
    const int bc  = blockIdx.x;
    const int b   = bc / C;
    const int c   = bc - b * C;
    const int tid = threadIdx.x;

    const float* __restrict__ clsb  = cls  + (size_t)b * N * C + c;
    const float* __restrict__ centb = cent + (size_t)b * N;
    const float* __restrict__ boxb  = boxes + (size_t)b * N * 4;

    // ---- load scores into registers ----
    float s[NPT];
#pragma unroll
    for (int j = 0; j < NPT; ++j) {
        int n = tid + j * BS;
        float v = -1.0f;
        if (n < N) {
            float cv = clsb[(size_t)n * C];
            if (cv > SCORE_THR) v = sqrtf(cv * centb[n]);   // combined = sqrt(cls*cent)
        }
        s[j] = v;
    }

    __shared__ float kx1[MAXDET], ky1[MAXDET], kx2[MAXDET], ky2[MAXDET];
    __shared__ float kscore[MAXDET];
    __shared__ int   kidx[MAXDET];
    __shared__ float redS[BS / 64];
    __shared__ int   redI[BS / 64];
    __shared__ float pbox[4];
    __shared__ float pscoreSh;
    __shared__ int   ctrl;
    __shared__ int   supFlag;

    const int lane = tid & 63;
    const int wid  = tid >> 6;
    const int NW   = BS / 64;
    int cnt = 0;

    const int maxIter = N + MAXDET + 2;   // safety bound; each iter consumes one candidate
    for (int iter = 0; iter < maxIter; ++iter) {
        // ---- block argmax with lowest-index tie-break ----
        float bs = -1.0f; int bi = 0x7fffffff;
#pragma unroll
        for (int j = 0; j < NPT; ++j) {
            if (s[j] > bs) { bs = s[j]; bi = tid + j * BS; }   // ascending j => lowest n on ties
        }
        for (int m = 1; m < 64; m <<= 1) {
            float os = __shfl_xor(bs, m);
            int   oi = __shfl_xor(bi, m);
            combineMax(bs, bi, os, oi);
        }
        if (lane == 0) { redS[wid] = bs; redI[wid] = bi; }
        __syncthreads();
        if (tid == 0) {
            float gs = redS[0]; int gi = redI[0];
            for (int w = 1; w < NW; ++w) combineMax(gs, gi, redS[w], redI[w]);
            supFlag = 0;
            if (gs <= 0.0f) {
                ctrl = -1;                 // no positive candidates left -> done
            } else {
                ctrl = gi; pscoreSh = gs;
                const float4 bx = *reinterpret_cast<const float4*>(boxb + (size_t)gi * 4);
                pbox[0] = bx.x; pbox[1] = bx.y; pbox[2] = bx.z; pbox[3] = bx.w;
            }
        }
        __syncthreads();
        const int P = ctrl;
        if (P < 0) break;

        // owner marks the examined candidate as consumed (compile-time indices only)
        if ((P & (BS - 1)) == tid) {
            const int jp = P >> 10;        // log2(BS)
#pragma unroll
            for (int j = 0; j < NPT; ++j) if (j == jp) s[j] = -1.0f;
        }

        // check picked box against kept list: kept box plays the reference's
        // "box" role (it was the eager pick), candidate plays "boxes" role.
        if (tid < cnt) {
            const float px1 = pbox[0], py1 = pbox[1], px2 = pbox[2], py2 = pbox[3];
            const float qx1 = kx1[tid], qy1 = ky1[tid], qx2 = kx2[tid], qy2 = ky2[tid];
            const float ix1 = fmaxf(qx1, px1), iy1 = fmaxf(qy1, py1);
            const float ix2 = fminf(qx2, px2), iy2 = fminf(qy2, py2);
            const float inter = fmaxf(ix2 - ix1, 0.0f) * fmaxf(iy2 - iy1, 0.0f);
            const float aq = (qx2 - qx1) * (qy2 - qy1);   // kept ("area")
            const float ap = (px2 - px1) * (py2 - py1);   // candidate ("areas")
            const float iou = inter / (aq + ap - inter + 1e-8f);   // exact ref assoc order
            if (iou > IOU_THR) supFlag = 1;
        }
        __syncthreads();
        if (supFlag == 0) {
            if (tid == 0) {
                kx1[cnt] = pbox[0]; ky1[cnt] = pbox[1];
                kx2[cnt] = pbox[2]; ky2[cnt] = pbox[3];
                kscore[cnt] = pscoreSh; kidx[cnt] = P;
            }
            ++cnt;                         // every thread mirrors the count
            if (cnt == MAXDET) break;
        }
    }

    for (int k = tid; k < cnt; k += BS) {
        keptIdx[(size_t)bc * MAXDET + k]   = kidx[k];
        keptScore[(size_t)bc * MAXDET + k] = kscore[k];
    }
    if (tid == 0) keptCnt[bc] = cnt;
}

// One wave per image: 16-way merge of the per-class kept lists (each already
// descending by construction), tie-break lowest flat index = c*N + anchor.
__global__ __launch_bounds__(64) void topk_kernel(
    const float* __restrict__ boxes, const int* __restrict__ keptIdx,
    const float* __restrict__ keptScore, const int* __restrict__ keptCnt,
    int B, int N, int C, float* __restrict__ out)
{
    const int b   = blockIdx.x;
    const int tid = threadIdx.x;

    __shared__ float fs[16 * MAXDET];
    __shared__ int   ff[16 * MAXDET];
    __shared__ float selS[MAXDET];
    __shared__ int   selF[MAXDET];
    __shared__ int   cnts[16];

    if (tid < C) cnts[tid] = keptCnt[b * C + tid];
    __syncthreads();

    const int total = C * MAXDET;
    for (int idx = tid; idx < total; idx += 64) {
        const int c = idx / MAXDET;
        const int k = idx - c * MAXDET;
        float v = -2.0f; int fl = 0x7fffffff;
        if (k < cnts[c]) {
            v  = keptScore[(size_t)(b * C + c) * MAXDET + k];
            fl = c * N + keptIdx[(size_t)(b * C + c) * MAXDET + k];
        }
        fs[idx] = v; ff[idx] = fl;
    }
    __syncthreads();

    int h = 0;   // this lane's class head (lanes >= C never supply candidates)
    for (int r = 0; r < MAXDET; ++r) {
        float v = -2.0f; int fl = 0x7fffffff;
        if (tid < C && h < MAXDET) { v = fs[tid * MAXDET + h]; fl = ff[tid * MAXDET + h]; }
        int wl = tid;
        for (int m = 1; m < 64; m <<= 1) {
            float ov  = __shfl_xor(v, m);
            int   ofl = __shfl_xor(fl, m);
            int   owl = __shfl_xor(wl, m);
            if (ov > v || (ov == v && ofl < fl)) { v = ov; fl = ofl; wl = owl; }
        }
        if (tid == wl) ++h;                 // winner advances its head
        if (tid == 0) { selS[r] = v; selF[r] = fl; }
    }
    __syncthreads();

    const int boff = b * MAXDET;
    for (int r = tid; r < MAXDET; r += 64) {
        const float sv = selS[r];
        const int   fl = selF[r];
        float4 bx = make_float4(-1.0f, -1.0f, -1.0f, -1.0f);
        float sc = -1.0f, lb = -1.0f;
        if (sv > 0.0f) {
            const int label  = fl / N;
            const int anchor = fl - label * N;
            bx = *reinterpret_cast<const float4*>(boxes + ((size_t)b * N + anchor) * 4);
            sc = sv; lb = (float)label;
        }
        *reinterpret_cast<float4*>(out + (size_t)(boff + r) * 4) = bx;
        out[(size_t)B * MAXDET * 4 + boff + r] = sc;   // scores block
        out[(size_t)B * MAXDET * 5 + boff + r] = lb;   // labels block (as f32)
    }
}

extern "C" void kernel_launch(void* const* d_in, const int* in_sizes, int n_in,
                              void* d_out, int out_size, void* d_ws, size_t ws_size,
                              hipStream_t stream) {
    const float* boxes = (const float*)d_in[0];
    const float* cls   = (const float*)d_in[1];
    const float* cent  = (const float*)d_in[2];
    float* out = (float*)d_out;

    const int B = out_size / (MAXDET * 6);        // boxes(4) + scores(1) + labels(1)
    const int N = in_sizes[2] / B;                // centerness is [B, N, 1]
    const int C = in_sizes[1] / in_sizes[2];      // classification is [B, N, C]
    if (B <= 0 || N <= 0 || C <= 0 || C > 16) return;

    // workspace layout (all small, ~308 KB)
    char* p = (char*)d_ws;
    const int BC = B * C;
    int*   keptIdx   = (int*)p;              p += (size_t)BC * MAXDET * sizeof(int);
    float* keptScore = (float*)p;            p += (size_t)BC * MAXDET * sizeof(float);
    int*   keptCnt   = (int*)p;              p += (size_t)BC * sizeof(int);
    if ((size_t)(p - (char*)d_ws) > ws_size) return;

    const int nptNeeded = (N + BS - 1) / BS;
    if (nptNeeded <= 49) {
        nms_kernel<49><<<BC, BS, 0, stream>>>(boxes, cls, cent, B, N, C,
                                              keptIdx, keptScore, keptCnt);
    } else if (nptNeeded <= 64) {
        nms_kernel<64><<<BC, BS, 0, stream>>>(boxes, cls, cent, B, N, C,
                                              keptIdx, keptScore, keptCnt);
    } else {
        return;   // unsupported N for this problem family
    }

    topk_kernel<<<B, 64, 0, stream>>>(boxes, keptIdx, keptScore, keptCnt, B, N, C, out);
}

// Round 3
// 548.009 us; speedup vs baseline: 2.3515x; 2.3515x over previous
//
#include <hip/hip_runtime.h>
#include <cstdint>
#include <cstddef>

#define MAXDET 300
#define IOU_THR 0.6f
#define SCORE_THR 0.05f
#define T0 0.9f          // combined-score compaction threshold (see theory; guarded by fallback)
#define CAP 2048         // per-class candidate capacity (expected ~1073, +4sigma ~1200)
#define BS 1024          // slow-path block size
#define CHUNK 512        // nms_fast LDS staging chunk

typedef unsigned int u32;
typedef unsigned long long u64;

// ============================ fast path ============================

// Pass 1: coalesced score compute + per-class candidate compaction.
// Each anchor's 16 class scores read as 4x float4 (64B contiguous).
// Candidates with combined >= T0 appended (unordered) to per-class lists as
// packed keys (score_bits<<32 | ~n) -- sort canonicalizes order later.
// Also counts total candidates (cls > 0.05) per class for the fallback check.
__global__ __launch_bounds__(256) void score_compact_kernel(
    const float* __restrict__ cls, const float* __restrict__ cent,
    int N, int C, int SPLIT,
    u64* __restrict__ candPacked, int* __restrict__ cntRaw, int* __restrict__ totalCand)
{
    const int b = blockIdx.x / SPLIT;
    const int s = blockIdx.x % SPLIT;
    const int chunk = (N + SPLIT - 1) / SPLIT;
    const int n0 = s * chunk;
    const int n1 = min(n0 + chunk, N);
    const int tid = threadIdx.x;

    __shared__ int locTot[16];
    if (tid < 16) locTot[tid] = 0;
    __syncthreads();

    int myTot[16];
#pragma unroll
    for (int c = 0; c < 16; ++c) myTot[c] = 0;

    for (int n = n0 + tid; n < n1; n += 256) {
        const float4* row = reinterpret_cast<const float4*>(cls + ((size_t)b * N + n) * 16);
        const float4 r0 = row[0], r1 = row[1], r2 = row[2], r3 = row[3];
        const float ce = cent[(size_t)b * N + n];
        float cv[16];
        cv[0] = r0.x; cv[1] = r0.y; cv[2] = r0.z; cv[3] = r0.w;
        cv[4] = r1.x; cv[5] = r1.y; cv[6] = r1.z; cv[7] = r1.w;
        cv[8] = r2.x; cv[9] = r2.y; cv[10] = r2.z; cv[11] = r2.w;
        cv[12] = r3.x; cv[13] = r3.y; cv[14] = r3.z; cv[15] = r3.w;
#pragma unroll
        for (int c = 0; c < 16; ++c) {
            const float v = cv[c];
            if (v > SCORE_THR) {
                myTot[c]++;
                const float comb = sqrtf(v * ce);   // exact ref expression
                if (comb >= T0) {
                    const int pos = atomicAdd(&cntRaw[b * 16 + c], 1);
                    if (pos < CAP) {
                        const u64 key = ((u64)__float_as_uint(comb) << 32)
                                      | (u32)(0xFFFFFFFFu - (u32)n);   // score desc, n asc
                        candPacked[((size_t)(b * 16 + c) << 11) + pos] = key;
                    }
                }
            }
        }
    }
#pragma unroll
    for (int c = 0; c < 16; ++c) atomicAdd(&locTot[c], myTot[c]);
    __syncthreads();
    if (tid < 16) atomicAdd(&totalCand[b * 16 + tid], locTot[tid]);
}

// Pass 2: per-class bitonic sort of the (<=2048) packed keys, descending.
// Keys stored inverted in LDS so a standard ascending bitonic sorts them.
__global__ __launch_bounds__(256) void sort_cand_kernel(
    u64* __restrict__ candPacked, const int* __restrict__ cntRaw)
{
    const int bc = blockIdx.x;
    const int use = min(cntRaw[bc], CAP);
    const int tid = threadIdx.x;
    __shared__ u64 key[CAP];
    u64* gbase = candPacked + ((size_t)bc << 11);

    for (int i = tid; i < CAP; i += 256)
        key[i] = (i < use) ? ~gbase[i] : ~0ULL;    // pads sort to the end

    for (int k = 2; k <= CAP; k <<= 1) {
        for (int j = k >> 1; j > 0; j >>= 1) {
            __syncthreads();
            for (int i = tid; i < CAP; i += 256) {
                const int l = i ^ j;
                if (l > i) {
                    const u64 a = key[i], bb = key[l];
                    const bool up = ((i & k) == 0);
                    if ((a > bb) == up) { key[i] = bb; key[l] = a; }
                }
            }
        }
    }
    __syncthreads();
    for (int i = tid; i < use; i += 256) gbase[i] = ~key[i];
}

// Pass 3: one wave per (b,c). Sequential greedy NMS over the sorted list:
// keep candidate iff IoU <= thr vs every previously-kept box (64 lanes check
// the kept list in parallel, SoA in LDS). Equivalent to the reference's
// eager argmax NMS; cap = 300 KEPT (suppressed candidates don't count).
__global__ __launch_bounds__(64) void nms_fast_kernel(
    const float* __restrict__ boxes, const u64* __restrict__ candPacked,
    const int* __restrict__ cntRaw, const int* __restrict__ totalCand,
    int N, int C,
    int* __restrict__ keptIdx, float* __restrict__ keptScore,
    int* __restrict__ keptCnt, int* __restrict__ flagInc)
{
    const int bc = blockIdx.x;
    const int b = bc / C;
    const int lane = threadIdx.x;
    const int raw = cntRaw[bc];
    const int use = min(raw, CAP);
    const float* __restrict__ boxb = boxes + (size_t)b * N * 4;

    __shared__ float kx1[MAXDET], ky1[MAXDET], kx2[MAXDET], ky2[MAXDET], ksc[MAXDET];
    __shared__ int   kix[MAXDET];
    __shared__ float4 cbox[CHUNK];
    __shared__ float  cscore[CHUNK];
    __shared__ int    cidx[CHUNK];

    int cnt = 0;
    for (int base = 0; base < use && cnt < MAXDET; base += CHUNK) {
        const int m = min(CHUNK, use - base);
        for (int t = lane; t < m; t += 64) {
            const u64 kk = candPacked[((size_t)bc << 11) + base + t];
            const int n = (int)(0xFFFFFFFFu - (u32)kk);
            cscore[t] = __uint_as_float((u32)(kk >> 32));
            cidx[t]   = n;
            cbox[t]   = *reinterpret_cast<const float4*>(boxb + (size_t)n * 4);
        }
        __syncthreads();
        for (int i = 0; i < m; ++i) {
            const float4 p = cbox[i];                      // broadcast read
            const float ap = (p.z - p.x) * (p.w - p.y);    // candidate area ("areas")
            bool sup = false;
            for (int kb = lane; kb < cnt; kb += 64) {
                const float qx1 = kx1[kb], qy1 = ky1[kb], qx2 = kx2[kb], qy2 = ky2[kb];
                const float ix1 = fmaxf(qx1, p.x), iy1 = fmaxf(qy1, p.y);
                const float ix2 = fminf(qx2, p.z), iy2 = fminf(qy2, p.w);
                const float inter = fmaxf(ix2 - ix1, 0.0f) * fmaxf(iy2 - iy1, 0.0f);
                const float aq = (qx2 - qx1) * (qy2 - qy1);           // kept ("area")
                const float iou = inter / (aq + ap - inter + 1e-8f);  // ref assoc order
                sup = sup || (iou > IOU_THR);
            }
            if (!__any(sup)) {
                if (lane == 0) {
                    kx1[cnt] = p.x; ky1[cnt] = p.y; kx2[cnt] = p.z; ky2[cnt] = p.w;
                    ksc[cnt] = cscore[i]; kix[cnt] = cidx[i];
                }
                ++cnt;
                if (cnt == MAXDET) break;
            }
        }
        __syncthreads();
    }

    for (int k = lane; k < cnt; k += 64) {
        keptIdx[bc * MAXDET + k]   = kix[k];
        keptScore[bc * MAXDET + k] = ksc[k];
    }
    if (lane == 0) {
        keptCnt[bc] = cnt;
        // incomplete iff cap overflow, or list exhausted below 300 kept while
        // candidates below T0 exist (they could still be picked by the ref).
        flagInc[bc] = (raw > CAP || (cnt < MAXDET && totalCand[bc] > use)) ? 1 : 0;
    }
}

// ==================== slow path (round-1, verified) ====================

__device__ __forceinline__ void combineMax(float& bs, int& bi, float os, int oi) {
    if (os > bs || (os == bs && oi < bi)) { bs = os; bi = oi; }
}

template<int NPT>
__global__ __launch_bounds__(BS) void nms_slow_kernel(
    const float* __restrict__ boxes, const float* __restrict__ cls,
    const float* __restrict__ cent, int B, int N, int C,
    int* __restrict__ keptIdx, float* __restrict__ keptScore, int* __restrict__ keptCnt,
    const int* __restrict__ flagInc)
{
    const int bc = blockIdx.x;
    if (flagInc != nullptr && flagInc[bc] == 0) return;   // fast path was complete
    const int b   = bc / C;
    const int c   = bc - b * C;
    const int tid = threadIdx.x;

    const float* __restrict__ clsb  = cls  + (size_t)b * N * C + c;
    const float* __restrict__ centb = cent + (size_t)b * N;
    const float* __restrict__ boxb  = boxes + (size_t)b * N * 4;

    float s[NPT];
#pragma unroll
    for (int j = 0; j < NPT; ++j) {
        int n = tid + j * BS;
        float v = -1.0f;
        if (n < N) {
            float cv = clsb[(size_t)n * C];
            if (cv > SCORE_THR) v = sqrtf(cv * centb[n]);
        }
        s[j] = v;
    }

    __shared__ float kx1[MAXDET], ky1[MAXDET], kx2[MAXDET], ky2[MAXDET];
    __shared__ float kscore[MAXDET];
    __shared__ int   kidx[MAXDET];
    __shared__ float redS[BS / 64];
    __shared__ int   redI[BS / 64];
    __shared__ float pbox[4];
    __shared__ float pscoreSh;
    __shared__ int   ctrl;
    __shared__ int   supFlag;

    const int lane = tid & 63;
    const int wid  = tid >> 6;
    const int NW   = BS / 64;
    int cnt = 0;

    const int maxIter = N + MAXDET + 2;
    for (int iter = 0; iter < maxIter; ++iter) {
        float bs = -1.0f; int bi = 0x7fffffff;
#pragma unroll
        for (int j = 0; j < NPT; ++j) {
            if (s[j] > bs) { bs = s[j]; bi = tid + j * BS; }
        }
        for (int m = 1; m < 64; m <<= 1) {
            float os = __shfl_xor(bs, m);
            int   oi = __shfl_xor(bi, m);
            combineMax(bs, bi, os, oi);
        }
        if (lane == 0) { redS[wid] = bs; redI[wid] = bi; }
        __syncthreads();
        if (tid == 0) {
            float gs = redS[0]; int gi = redI[0];
            for (int w = 1; w < NW; ++w) combineMax(gs, gi, redS[w], redI[w]);
            supFlag = 0;
            if (gs <= 0.0f) {
                ctrl = -1;
            } else {
                ctrl = gi; pscoreSh = gs;
                const float4 bx = *reinterpret_cast<const float4*>(boxb + (size_t)gi * 4);
                pbox[0] = bx.x; pbox[1] = bx.y; pbox[2] = bx.z; pbox[3] = bx.w;
            }
        }
        __syncthreads();
        const int P = ctrl;
        if (P < 0) break;

        if ((P & (BS - 1)) == tid) {
            const int jp = P >> 10;
#pragma unroll
            for (int j = 0; j < NPT; ++j) if (j == jp) s[j] = -1.0f;
        }

        if (tid < cnt) {
            const float px1 = pbox[0], py1 = pbox[1], px2 = pbox[2], py2 = pbox[3];
            const float qx1 = kx1[tid], qy1 = ky1[tid], qx2 = kx2[tid], qy2 = ky2[tid];
            const float ix1 = fmaxf(qx1, px1), iy1 = fmaxf(qy1, py1);
            const float ix2 = fminf(qx2, px2), iy2 = fminf(qy2, py2);
            const float inter = fmaxf(ix2 - ix1, 0.0f) * fmaxf(iy2 - iy1, 0.0f);
            const float aq = (qx2 - qx1) * (qy2 - qy1);
            const float ap = (px2 - px1) * (py2 - py1);
            const float iou = inter / (aq + ap - inter + 1e-8f);
            if (iou > IOU_THR) supFlag = 1;
        }
        __syncthreads();
        if (supFlag == 0) {
            if (tid == 0) {
                kx1[cnt] = pbox[0]; ky1[cnt] = pbox[1];
                kx2[cnt] = pbox[2]; ky2[cnt] = pbox[3];
                kscore[cnt] = pscoreSh; kidx[cnt] = P;
            }
            ++cnt;
            if (cnt == MAXDET) break;
        }
    }

    for (int k = tid; k < cnt; k += BS) {
        keptIdx[(size_t)bc * MAXDET + k]   = kidx[k];
        keptScore[(size_t)bc * MAXDET + k] = kscore[k];
    }
    if (tid == 0) keptCnt[bc] = cnt;
}

// ==================== final top-300 (bitonic over 16x512) ====================

__global__ __launch_bounds__(1024) void topk_kernel(
    const float* __restrict__ boxes, const int* __restrict__ keptIdx,
    const float* __restrict__ keptScore, const int* __restrict__ keptCnt,
    int B, int N, int C, float* __restrict__ out)
{
    const int b   = blockIdx.x;
    const int tid = threadIdx.x;

    __shared__ u64 key[8192];
    __shared__ int cnts[16];
    if (tid < C) cnts[tid] = keptCnt[b * C + tid];
    __syncthreads();

    for (int i = tid; i < 8192; i += 1024) {
        const int c = i >> 9;          // 16 slots of 512 (cnt <= 300 < 512)
        const int k = i & 511;
        u64 v = ~0ULL;
        if (c < C && k < cnts[c]) {
            const float sc = keptScore[(b * C + c) * MAXDET + k];
            const int   fl = c * N + keptIdx[(b * C + c) * MAXDET + k];
            v = ~(((u64)__float_as_uint(sc) << 32) | (u32)(0xFFFFFFFFu - (u32)fl));
        }
        key[i] = v;
    }

    for (int k = 2; k <= 8192; k <<= 1) {
        for (int j = k >> 1; j > 0; j >>= 1) {
            __syncthreads();
            for (int i = tid; i < 8192; i += 1024) {
                const int l = i ^ j;
                if (l > i) {
                    const u64 a = key[i], bb = key[l];
                    const bool up = ((i & k) == 0);
                    if ((a > bb) == up) { key[i] = bb; key[l] = a; }
                }
            }
        }
    }
    __syncthreads();

    const int boff = b * MAXDET;
    for (int r = tid; r < MAXDET; r += 1024) {
        const u64 kk = ~key[r];
        const float sc = __uint_as_float((u32)(kk >> 32));
        float4 bx = make_float4(-1.0f, -1.0f, -1.0f, -1.0f);
        float so = -1.0f, lo = -1.0f;
        if (sc > 0.0f) {
            const int fl = (int)(0xFFFFFFFFu - (u32)kk);
            const int label  = fl / N;
            const int anchor = fl - label * N;
            bx = *reinterpret_cast<const float4*>(boxes + ((size_t)b * N + anchor) * 4);
            so = sc; lo = (float)label;
        }
        *reinterpret_cast<float4*>(out + (size_t)(boff + r) * 4) = bx;
        out[(size_t)B * MAXDET * 4 + boff + r] = so;
        out[(size_t)B * MAXDET * 5 + boff + r] = lo;
    }
}

// ============================ launcher ============================

extern "C" void kernel_launch(void* const* d_in, const int* in_sizes, int n_in,
                              void* d_out, int out_size, void* d_ws, size_t ws_size,
                              hipStream_t stream) {
    const float* boxes = (const float*)d_in[0];
    const float* cls   = (const float*)d_in[1];
    const float* cent  = (const float*)d_in[2];
    float* out = (float*)d_out;

    const int B = out_size / (MAXDET * 6);
    if (B <= 0) return;
    const int N = in_sizes[2] / B;
    const int C = in_sizes[1] / in_sizes[2];
    if (N <= 0 || C <= 0 || C > 16) return;
    const int BC = B * C;

    // workspace layout (kept arrays first so the slow-only path fits small ws)
    char* base = (char*)d_ws;
    size_t off = 0;
    int*   keptIdx   = (int*)(base + off);   off += (size_t)BC * MAXDET * sizeof(int);
    float* keptScore = (float*)(base + off); off += (size_t)BC * MAXDET * sizeof(float);
    int*   keptCnt   = (int*)(base + off);   off += (size_t)BC * sizeof(int);
    int*   flagInc   = (int*)(base + off);   off += (size_t)BC * sizeof(int);
    const size_t slowNeed = off;
    int*   cntRaw    = (int*)(base + off);   off += (size_t)BC * sizeof(int);
    int*   totalCand = (int*)(base + off);   off += (size_t)BC * sizeof(int);
    off = (off + 7) & ~(size_t)7;
    u64*   candPacked = (u64*)(base + off);  off += (size_t)BC * CAP * sizeof(u64);
    const size_t fastNeed = off;

    const int nptNeeded = (N + BS - 1) / BS;
    if (nptNeeded > 64) return;   // outside this problem family

    const bool fast = (C == 16) && (ws_size >= fastNeed);

    if (fast) {
        hipMemsetAsync(cntRaw, 0, 2 * (size_t)BC * sizeof(int), stream);  // cntRaw+totalCand
        const int SPLIT = 64;
        score_compact_kernel<<<B * SPLIT, 256, 0, stream>>>(
            cls, cent, N, C, SPLIT, candPacked, cntRaw, totalCand);
        sort_cand_kernel<<<BC, 256, 0, stream>>>(candPacked, cntRaw);
        nms_fast_kernel<<<BC, 64, 0, stream>>>(
            boxes, candPacked, cntRaw, totalCand, N, C,
            keptIdx, keptScore, keptCnt, flagInc);
        // correctness insurance: redoes any class the fast path flagged
        if (nptNeeded <= 49)
            nms_slow_kernel<49><<<BC, BS, 0, stream>>>(boxes, cls, cent, B, N, C,
                                                       keptIdx, keptScore, keptCnt, flagInc);
        else
            nms_slow_kernel<64><<<BC, BS, 0, stream>>>(boxes, cls, cent, B, N, C,
                                                       keptIdx, keptScore, keptCnt, flagInc);
    } else {
        if (ws_size < slowNeed) return;
        if (nptNeeded <= 49)
            nms_slow_kernel<49><<<BC, BS, 0, stream>>>(boxes, cls, cent, B, N, C,
                                                       keptIdx, keptScore, keptCnt, nullptr);
        else
            nms_slow_kernel<64><<<BC, BS, 0, stream>>>(boxes, cls, cent, B, N, C,
                                                       keptIdx, keptScore, keptCnt, nullptr);
    }

    topk_kernel<<<B, 1024, 0, stream>>>(boxes, keptIdx, keptScore, keptCnt, B, N, C, out);
}

// Round 5
// 285.398 us; speedup vs baseline: 4.5152x; 1.9202x over previous
//
#include <hip/hip_runtime.h>
#include <cstdint>
#include <cstddef>

#define MAXDET 300
#define IOU_THR 0.6f
#define SCORE_THR 0.05f
#define T0 0.9f          // combined-score compaction threshold (fallback-guarded)
#define CAP 2048         // per-class candidate capacity (expected ~1075)
#define SCAN 512         // NMS scan window over sorted candidates (kept<=300 => examined ~300)
#define LCAP 64          // per-block per-class LDS list capacity (expected ~8.4)
#define SPLIT 128        // blocks per image in score pass
#define BS 1024          // slow-path block size

typedef unsigned int u32;
typedef unsigned long long u64;

// ============================ fast path ============================

// Pass 1: coalesced score compute + LDS-aggregated per-class compaction.
// 4 lanes per anchor (one float4 of classes each). Candidates (comb >= T0)
// buffered in per-class LDS lists, flushed with ONE global atomicAdd per
// class per block (contiguous range) + coalesced writes. This removes the
// per-candidate contended global atomic that dominated round 3 (222 us).
__global__ __launch_bounds__(256) void score_compact_kernel(
    const float* __restrict__ cls, const float* __restrict__ cent,
    int N, int C,
    u64* __restrict__ candPacked, int* __restrict__ cntRaw, int* __restrict__ totalCand)
{
    const int b = blockIdx.x / SPLIT;
    const int s = blockIdx.x % SPLIT;
    const int chunk = (N + SPLIT - 1) / SPLIT;
    const int n0 = s * chunk;
    const int n1 = min(n0 + chunk, N);
    const int tid = threadIdx.x;
    const int q  = tid & 3;        // quarter-row: classes 4q..4q+3
    const int ar = tid >> 2;       // anchor offset within 64-anchor tile

    __shared__ int lcnt[16];
    __shared__ int ltot[16];
    __shared__ int lbase[16];
    __shared__ u64 lbuf[16][LCAP];

    if (tid < 16) { lcnt[tid] = 0; ltot[tid] = 0; }
    __syncthreads();

    int myTot[4] = {0, 0, 0, 0};
    for (int n = n0 + ar; n < n1; n += 64) {
        const float4 r = *reinterpret_cast<const float4*>(
            cls + ((size_t)b * N + n) * 16 + q * 4);
        const float ce = cent[(size_t)b * N + n];
        const float cv[4] = {r.x, r.y, r.z, r.w};
#pragma unroll
        for (int u = 0; u < 4; ++u) {
            const float v = cv[u];
            if (v > SCORE_THR) {
                myTot[u]++;
                const float prod = v * ce;
                if (prod >= 0.80f) {                       // conservative pre-filter
                    const float comb = sqrtf(prod);        // exact ref expression
                    if (comb >= T0) {                      // exact boundary test
                        const int c = 4 * q + u;
                        const u64 key = ((u64)__float_as_uint(comb) << 32)
                                      | (u32)(0xFFFFFFFFu - (u32)n);  // score desc, n asc
                        const int lp = atomicAdd(&lcnt[c], 1);
                        if (lp < LCAP) {
                            lbuf[c][lp] = key;
                        } else {  // overflow (astronomically rare): direct append
                            const int pos = atomicAdd(&cntRaw[b * 16 + c], 1);
                            if (pos < CAP)
                                candPacked[((size_t)(b * 16 + c) << 11) + pos] = key;
                        }
                    }
                }
            }
        }
    }
#pragma unroll
    for (int u = 0; u < 4; ++u) atomicAdd(&ltot[4 * q + u], myTot[u]);
    __syncthreads();

    if (tid < 16) {
        const int m = min(lcnt[tid], LCAP);
        lbase[tid] = atomicAdd(&cntRaw[b * 16 + tid], m);   // reserve range
        atomicAdd(&totalCand[b * 16 + tid], ltot[tid]);
    }
    __syncthreads();

    for (int idx = tid; idx < 16 * LCAP; idx += 256) {      // coalesced flush
        const int c = idx >> 6;            // LCAP == 64
        const int k = idx & 63;
        if (k < min(lcnt[c], LCAP)) {
            const int pos = lbase[c] + k;
            if (pos < CAP)
                candPacked[((size_t)(b * 16 + c) << 11) + pos] = lbuf[c][k];
        }
    }
}

// Pass 2 (fused sort + NMS), one 1024-thread block per (b,c):
//  a) bitonic sort of <=2048 packed keys (1 CE/thread/pass, 66 passes)
//  b) gather boxes of top-SCAN candidates
//  c) 512x512 suppression bitmask via __ballot (row i: bits j with
//     IoU(box_i, box_j) > thr, exact reference association order)
//  d) wave-0 serial greedy scan: keep i iff its bit not set; on keep,
//     OR row i into the removal bitmap (8 u64 words, one per lane 0..7).
// Identical arithmetic + tie-breaks to the reference's eager argmax NMS.
__global__ __launch_bounds__(1024) void sort_nms_kernel(
    const float* __restrict__ boxes, u64* __restrict__ candPacked,
    const int* __restrict__ cntRaw, const int* __restrict__ totalCand,
    int N, int C,
    int* __restrict__ keptIdx, float* __restrict__ keptScore,
    int* __restrict__ keptCnt, int* __restrict__ flagInc)
{
    const int bc  = blockIdx.x;
    const int b   = bc / C;
    const int tid = threadIdx.x;
    const int wv  = tid >> 6;
    const int ln  = tid & 63;
    const int raw = cntRaw[bc];
    const int use = min(raw, CAP);
    const float* __restrict__ boxb = boxes + (size_t)b * N * 4;
    const u64* __restrict__ gbase = candPacked + ((size_t)bc << 11);

    __shared__ u64    key[CAP];        // 16 KB, inverted keys (ascending sort)
    __shared__ float4 sbox[SCAN];      //  8 KB
    __shared__ u64    mask[SCAN][8];   // 32 KB
    __shared__ float  ksc[MAXDET];
    __shared__ int    kix[MAXDET];
    __shared__ int    cntSh;

    for (int i = tid; i < CAP; i += 1024)
        key[i] = (i < use) ? ~gbase[i] : ~0ULL;
    __syncthreads();

    for (int k = 2; k <= CAP; k <<= 1) {
        for (int j = k >> 1; j > 0; j >>= 1) {
            const int i = ((tid & ~(j - 1)) << 1) | (tid & (j - 1));
            const int l = i | j;
            const u64 a = key[i], bb = key[l];
            const bool up = ((i & k) == 0);
            if ((a > bb) == up) { key[i] = bb; key[l] = a; }
            __syncthreads();
        }
    }

    const int scanN = min(use, SCAN);
    if (tid < SCAN) {
        float4 bx = make_float4(0.f, 0.f, 0.f, 0.f);
        if (tid < scanN) {
            const u64 kk = ~key[tid];
            const int n = (int)(0xFFFFFFFFu - (u32)kk);
            bx = *reinterpret_cast<const float4*>(boxb + (size_t)n * 4);
        }
        sbox[tid] = bx;
    }
    __syncthreads();

    // suppression bitmask: wave wv handles words wd = wv, wv+16, ...
    for (int wd = wv; wd < SCAN * 8; wd += 16) {
        const int i = wd >> 3;
        const int w = wd & 7;
        const int j = w * 64 + ln;
        bool sup = false;
        if (i < scanN && j < scanN && j != i) {
            const float4 p = sbox[i];   // kept box ("box" role)
            const float4 qb = sbox[j];  // later candidate ("boxes" role)
            const float ix1 = fmaxf(p.x, qb.x), iy1 = fmaxf(p.y, qb.y);
            const float ix2 = fminf(p.z, qb.z), iy2 = fminf(p.w, qb.w);
            const float inter = fmaxf(ix2 - ix1, 0.f) * fmaxf(iy2 - iy1, 0.f);
            const float ai = (p.z - p.x) * (p.w - p.y);
            const float aj = (qb.z - qb.x) * (qb.w - qb.y);
            sup = (inter / (ai + aj - inter + 1e-8f)) > IOU_THR;  // ref assoc order
        }
        const u64 bal = __ballot(sup);
        if (ln == 0) mask[i][w] = bal;
    }
    __syncthreads();

    if (wv == 0) {
        u64 remv = 0ULL;                 // lane l<8 owns removal word l
        int cnt = 0;
        u64 rowCur = (ln < 8 && scanN > 0) ? mask[0][ln] : 0ULL;
        for (int i = 0; i < scanN; ++i) {
            const u64 rowNext = (ln < 8 && (i + 1) < scanN) ? mask[i + 1][ln] : 0ULL;
            const int wi = i >> 6, bi = i & 63;
            const u32 rb = (u32)((remv >> bi) & 1ULL);
            const u32 removed = __shfl(rb, wi);
            if (!removed) {
                remv |= rowCur;
                if (ln == 0) {
                    const u64 kk = ~key[i];
                    ksc[cnt] = __uint_as_float((u32)(kk >> 32));
                    kix[cnt] = (int)(0xFFFFFFFFu - (u32)kk);
                }
                ++cnt;
                if (cnt == MAXDET) break;
            }
            rowCur = rowNext;
        }
        if (ln == 0) cntSh = cnt;
    }
    __syncthreads();

    const int cnt = cntSh;
    for (int k = tid; k < cnt; k += 1024) {
        keptIdx[bc * MAXDET + k]   = kix[k];
        keptScore[bc * MAXDET + k] = ksc[k];
    }
    if (tid == 0) {
        keptCnt[bc] = cnt;
        flagInc[bc] = (raw > CAP
                       || (cnt < MAXDET && totalCand[bc] > use)   // pool cut by T0
                       || (cnt < MAXDET && use > scanN)           // window exhausted
                      ) ? 1 : 0;
    }
}

// ==================== slow path (round-1, verified) ====================

__device__ __forceinline__ void combineMax(float& bs, int& bi, float os, int oi) {
    if (os > bs || (os == bs && oi < bi)) { bs = os; bi = oi; }
}

template<int NPT>
__global__ __launch_bounds__(BS) void nms_slow_kernel(
    const float* __restrict__ boxes, const float* __restrict__ cls,
    const float* __restrict__ cent, int B, int N, int C,
    int* __restrict__ keptIdx, float* __restrict__ keptScore, int* __restrict__ keptCnt,
    const int* __restrict__ flagInc)
{
    const int bc = blockIdx.x;
    if (flagInc != nullptr && flagInc[bc] == 0) return;   // fast path was complete
    const int b   = bc / C;
    const int c   = bc - b * C;
    const int tid = threadIdx.x;

    const float* __restrict__ clsb  = cls  + (size_t)b * N * C + c;
    const float* __restrict__ centb = cent + (size_t)b * N;
    const float* __restrict__ boxb  = boxes + (size_t)b * N * 4;

    float s[NPT];
#pragma unroll
    for (int j = 0; j < NPT; ++j) {
        int n = tid + j * BS;
        float v = -1.0f;
        if (n < N) {
            float cv = clsb[(size_t)n * C];
            if (cv > SCORE_THR) v = sqrtf(cv * centb[n]);
        }
        s[j] = v;
    }

    __shared__ float kx1[MAXDET], ky1[MAXDET], kx2[MAXDET], ky2[MAXDET];
    __shared__ float kscore[MAXDET];
    __shared__ int   kidx[MAXDET];
    __shared__ float redS[BS / 64];
    __shared__ int   redI[BS / 64];
    __shared__ float pbox[4];
    __shared__ float pscoreSh;
    __shared__ int   ctrl;
    __shared__ int   supFlag;

    const int lane = tid & 63;
    const int wid  = tid >> 6;
    const int NW   = BS / 64;
    int cnt = 0;

    const int maxIter = N + MAXDET + 2;
    for (int iter = 0; iter < maxIter; ++iter) {
        float bs = -1.0f; int bi = 0x7fffffff;
#pragma unroll
        for (int j = 0; j < NPT; ++j) {
            if (s[j] > bs) { bs = s[j]; bi = tid + j * BS; }
        }
        for (int m = 1; m < 64; m <<= 1) {
            float os = __shfl_xor(bs, m);
            int   oi = __shfl_xor(bi, m);
            combineMax(bs, bi, os, oi);
        }
        if (lane == 0) { redS[wid] = bs; redI[wid] = bi; }
        __syncthreads();
        if (tid == 0) {
            float gs = redS[0]; int gi = redI[0];
            for (int w = 1; w < NW; ++w) combineMax(gs, gi, redS[w], redI[w]);
            supFlag = 0;
            if (gs <= 0.0f) {
                ctrl = -1;
            } else {
                ctrl = gi; pscoreSh = gs;
                const float4 bx = *reinterpret_cast<const float4*>(boxb + (size_t)gi * 4);
                pbox[0] = bx.x; pbox[1] = bx.y; pbox[2] = bx.z; pbox[3] = bx.w;
            }
        }
        __syncthreads();
        const int P = ctrl;
        if (P < 0) break;

        if ((P & (BS - 1)) == tid) {
            const int jp = P >> 10;
#pragma unroll
            for (int j = 0; j < NPT; ++j) if (j == jp) s[j] = -1.0f;
        }

        if (tid < cnt) {
            const float px1 = pbox[0], py1 = pbox[1], px2 = pbox[2], py2 = pbox[3];
            const float qx1 = kx1[tid], qy1 = ky1[tid], qx2 = kx2[tid], qy2 = ky2[tid];
            const float ix1 = fmaxf(qx1, px1), iy1 = fmaxf(qy1, py1);
            const float ix2 = fminf(qx2, px2), iy2 = fminf(qy2, py2);
            const float inter = fmaxf(ix2 - ix1, 0.0f) * fmaxf(iy2 - iy1, 0.0f);
            const float aq = (qx2 - qx1) * (qy2 - qy1);
            const float ap = (px2 - px1) * (py2 - py1);
            const float iou = inter / (aq + ap - inter + 1e-8f);
            if (iou > IOU_THR) supFlag = 1;
        }
        __syncthreads();
        if (supFlag == 0) {
            if (tid == 0) {
                kx1[cnt] = pbox[0]; ky1[cnt] = pbox[1];
                kx2[cnt] = pbox[2]; ky2[cnt] = pbox[3];
                kscore[cnt] = pscoreSh; kidx[cnt] = P;
            }
            ++cnt;
            if (cnt == MAXDET) break;
        }
    }

    for (int k = tid; k < cnt; k += BS) {
        keptIdx[(size_t)bc * MAXDET + k]   = kidx[k];
        keptScore[(size_t)bc * MAXDET + k] = kscore[k];
    }
    if (tid == 0) keptCnt[bc] = cnt;
}

// ==================== final top-300 (bitonic over 16x512) ====================

__global__ __launch_bounds__(1024) void topk_kernel(
    const float* __restrict__ boxes, const int* __restrict__ keptIdx,
    const float* __restrict__ keptScore, const int* __restrict__ keptCnt,
    int B, int N, int C, float* __restrict__ out)
{
    const int b   = blockIdx.x;
    const int tid = threadIdx.x;

    __shared__ u64 key[8192];
    __shared__ int cnts[16];
    if (tid < C) cnts[tid] = keptCnt[b * C + tid];
    __syncthreads();

    for (int i = tid; i < 8192; i += 1024) {
        const int c = i >> 9;          // 16 slots of 512 (cnt <= 300 < 512)
        const int k = i & 511;
        u64 v = ~0ULL;
        if (c < C && k < cnts[c]) {
            const float sc = keptScore[(b * C + c) * MAXDET + k];
            const int   fl = c * N + keptIdx[(b * C + c) * MAXDET + k];
            v = ~(((u64)__float_as_uint(sc) << 32) | (u32)(0xFFFFFFFFu - (u32)fl));
        }
        key[i] = v;
    }

    for (int k = 2; k <= 8192; k <<= 1) {
        for (int j = k >> 1; j > 0; j >>= 1) {
            __syncthreads();
            for (int i = tid; i < 8192; i += 1024) {
                const int l = i ^ j;
                if (l > i) {
                    const u64 a = key[i], bb = key[l];
                    const bool up = ((i & k) == 0);
                    if ((a > bb) == up) { key[i] = bb; key[l] = a; }
                }
            }
        }
    }
    __syncthreads();

    const int boff = b * MAXDET;
    for (int r = tid; r < MAXDET; r += 1024) {
        const u64 kk = ~key[r];
        const float sc = __uint_as_float((u32)(kk >> 32));
        float4 bx = make_float4(-1.0f, -1.0f, -1.0f, -1.0f);
        float so = -1.0f, lo = -1.0f;
        if (sc > 0.0f) {
            const int fl = (int)(0xFFFFFFFFu - (u32)kk);
            const int label  = fl / N;
            const int anchor = fl - label * N;
            bx = *reinterpret_cast<const float4*>(boxes + ((size_t)b * N + anchor) * 4);
            so = sc; lo = (float)label;
        }
        *reinterpret_cast<float4*>(out + (size_t)(boff + r) * 4) = bx;
        out[(size_t)B * MAXDET * 4 + boff + r] = so;
        out[(size_t)B * MAXDET * 5 + boff + r] = lo;
    }
}

// ============================ launcher ============================

extern "C" void kernel_launch(void* const* d_in, const int* in_sizes, int n_in,
                              void* d_out, int out_size, void* d_ws, size_t ws_size,
                              hipStream_t stream) {
    const float* boxes = (const float*)d_in[0];
    const float* cls   = (const float*)d_in[1];
    const float* cent  = (const float*)d_in[2];
    float* out = (float*)d_out;

    const int B = out_size / (MAXDET * 6);
    if (B <= 0) return;
    const int N = in_sizes[2] / B;
    const int C = in_sizes[1] / in_sizes[2];
    if (N <= 0 || C <= 0 || C > 16) return;
    const int BC = B * C;

    char* base = (char*)d_ws;
    size_t off = 0;
    int*   keptIdx   = (int*)(base + off);   off += (size_t)BC * MAXDET * sizeof(int);
    float* keptScore = (float*)(base + off); off += (size_t)BC * MAXDET * sizeof(float);
    int*   keptCnt   = (int*)(base + off);   off += (size_t)BC * sizeof(int);
    int*   flagInc   = (int*)(base + off);   off += (size_t)BC * sizeof(int);
    const size_t slowNeed = off;
    int*   cntRaw    = (int*)(base + off);   off += (size_t)BC * sizeof(int);
    int*   totalCand = (int*)(base + off);   off += (size_t)BC * sizeof(int);
    off = (off + 7) & ~(size_t)7;
    u64*   candPacked = (u64*)(base + off);  off += (size_t)BC * CAP * sizeof(u64);
    const size_t fastNeed = off;

    const int nptNeeded = (N + BS - 1) / BS;
    if (nptNeeded > 64) return;

    const bool fast = (C == 16) && (ws_size >= fastNeed);

    if (fast) {
        hipMemsetAsync(cntRaw, 0, 2 * (size_t)BC * sizeof(int), stream);
        score_compact_kernel<<<B * SPLIT, 256, 0, stream>>>(
            cls, cent, N, C, candPacked, cntRaw, totalCand);
        sort_nms_kernel<<<BC, 1024, 0, stream>>>(
            boxes, candPacked, cntRaw, totalCand, N, C,
            keptIdx, keptScore, keptCnt, flagInc);
        if (nptNeeded <= 49)
            nms_slow_kernel<49><<<BC, BS, 0, stream>>>(boxes, cls, cent, B, N, C,
                                                       keptIdx, keptScore, keptCnt, flagInc);
        else
            nms_slow_kernel<64><<<BC, BS, 0, stream>>>(boxes, cls, cent, B, N, C,
                                                       keptIdx, keptScore, keptCnt, flagInc);
    } else {
        if (ws_size < slowNeed) return;
        if (nptNeeded <= 49)
            nms_slow_kernel<49><<<BC, BS, 0, stream>>>(boxes, cls, cent, B, N, C,
                                                       keptIdx, keptScore, keptCnt, nullptr);
        else
            nms_slow_kernel<64><<<BC, BS, 0, stream>>>(boxes, cls, cent, B, N, C,
                                                       keptIdx, keptScore, keptCnt, nullptr);
    }

    topk_kernel<<<B, 1024, 0, stream>>>(boxes, keptIdx, keptScore, keptCnt, B, N, C, out);
}

// Round 6
// 229.629 us; speedup vs baseline: 5.6117x; 1.2429x over previous
//
#include <hip/hip_runtime.h>
#include <cstdint>
#include <cstddef>

#define MAXDET 300
#define IOU_THR 0.6f
#define SCORE_THR 0.05f
#define T0 0.9f          // combined-score compaction threshold (fallback-guarded)
#define CAP 2048         // per-class candidate capacity (expected ~1075)
#define SCAN 512         // NMS scan window over sorted candidates (examined ~345)
#define LCAP 64          // per-block per-class LDS list capacity in score pass
#define SPLIT 128        // blocks per image in score pass
#define BS 1024          // slow-path block size
#define NBUCK 1024       // bucket-sort bins
#define KEYS_MAX 576     // SCAN + slack for the straddling bucket
#define BITS_BASE 0x3F666666u   // float bits of 0.9f (all kept scores >= 0.9)

typedef unsigned int u32;
typedef unsigned long long u64;

// ============================ fast path ============================

// Pass 1: coalesced score compute + LDS-aggregated per-class compaction.
__global__ __launch_bounds__(256) void score_compact_kernel(
    const float* __restrict__ cls, const float* __restrict__ cent,
    int N, int C,
    u64* __restrict__ candPacked, int* __restrict__ cntRaw, int* __restrict__ totalCand)
{
    const int b = blockIdx.x / SPLIT;
    const int s = blockIdx.x % SPLIT;
    const int chunk = (N + SPLIT - 1) / SPLIT;
    const int n0 = s * chunk;
    const int n1 = min(n0 + chunk, N);
    const int tid = threadIdx.x;
    const int q  = tid & 3;        // quarter-row: classes 4q..4q+3
    const int ar = tid >> 2;       // anchor offset within 64-anchor tile

    __shared__ int lcnt[16];
    __shared__ int ltot[16];
    __shared__ int lbase[16];
    __shared__ u64 lbuf[16][LCAP];

    if (tid < 16) { lcnt[tid] = 0; ltot[tid] = 0; }
    __syncthreads();

    int myTot[4] = {0, 0, 0, 0};
    for (int n = n0 + ar; n < n1; n += 64) {
        const float4 r = *reinterpret_cast<const float4*>(
            cls + ((size_t)b * N + n) * 16 + q * 4);
        const float ce = cent[(size_t)b * N + n];
        const float cv[4] = {r.x, r.y, r.z, r.w};
#pragma unroll
        for (int u = 0; u < 4; ++u) {
            const float v = cv[u];
            if (v > SCORE_THR) {
                myTot[u]++;
                const float prod = v * ce;
                if (prod >= 0.80f) {                       // conservative pre-filter
                    const float comb = sqrtf(prod);        // exact ref expression
                    if (comb >= T0) {
                        const int c = 4 * q + u;
                        const u64 key = ((u64)__float_as_uint(comb) << 32)
                                      | (u32)(0xFFFFFFFFu - (u32)n);  // score desc, n asc
                        const int lp = atomicAdd(&lcnt[c], 1);
                        if (lp < LCAP) {
                            lbuf[c][lp] = key;
                        } else {  // overflow (astronomically rare): direct append
                            const int pos = atomicAdd(&cntRaw[b * 16 + c], 1);
                            if (pos < CAP)
                                candPacked[((size_t)(b * 16 + c) << 11) + pos] = key;
                        }
                    }
                }
            }
        }
    }
#pragma unroll
    for (int u = 0; u < 4; ++u) atomicAdd(&ltot[4 * q + u], myTot[u]);
    __syncthreads();

    if (tid < 16) {
        const int m = min(lcnt[tid], LCAP);
        lbase[tid] = atomicAdd(&cntRaw[b * 16 + tid], m);   // reserve range
        atomicAdd(&totalCand[b * 16 + tid], ltot[tid]);
    }
    __syncthreads();

    for (int idx = tid; idx < 16 * LCAP; idx += 256) {      // coalesced flush
        const int c = idx >> 6;            // LCAP == 64
        const int k = idx & 63;
        if (k < min(lcnt[c], LCAP)) {
            const int pos = lbase[c] + k;
            if (pos < CAP)
                candPacked[((size_t)(b * 16 + c) << 11) + pos] = lbuf[c][k];
        }
    }
}

// Pass 2 (fused bucket-sort + mask + chunked NMS), one 1024-thread block per (b,c).
//  a) bucket sort: scores in [0.9,1] -> mantissa-bit buckets (monotonic), LDS
//     count + Hillis-Steele scan + scatter + per-bucket insertion fix-up.
//  b) SoA box gather + areas for top-SCAN.
//  c) UPPER-TRIANGULAR 512x512 suppression mask via __ballot (IoU is bit-exact
//     symmetric: fmaxf/fminf/add all commutative, identical association order).
//  d) chunked greedy resolve: per 64-chunk, register bitmap + ballot chain
//     (no memory ops in the serial chain); cross-chunk via shfl OR-reduce.
// Identical keep-set + order to the reference's eager argmax NMS.
__global__ __launch_bounds__(1024) void sort_nms_kernel(
    const float* __restrict__ boxes, const u64* __restrict__ candPacked,
    const int* __restrict__ cntRaw, const int* __restrict__ totalCand,
    int N, int C,
    int* __restrict__ keptIdx, float* __restrict__ keptScore,
    int* __restrict__ keptCnt, int* __restrict__ flagInc)
{
    const int bc  = blockIdx.x;
    const int b   = bc / C;
    const int tid = threadIdx.x;
    const int wv  = tid >> 6;
    const int ln  = tid & 63;
    const int raw = cntRaw[bc];
    const int use = min(raw, CAP);
    const int scanN = min(use, SCAN);
    const float* __restrict__ boxb = boxes + (size_t)b * N * 4;
    const u64* __restrict__ gbase = candPacked + ((size_t)bc << 11);

    __shared__ u64   keyS[KEYS_MAX];                       // 4.5 KB sorted keys
    __shared__ float sx1[SCAN], sy1[SCAN], sx2[SCAN], sy2[SCAN], sar[SCAN]; // 10 KB
    __shared__ int   scA[NBUCK];                           // 4 KB
    __shared__ int   scB[NBUCK];                           // 4 KB
    __shared__ u64   mask[SCAN][9];                        // 36 KB (pad 9 vs 8)
    __shared__ float ksc[MAXDET];
    __shared__ int   kix[MAXDET];
    __shared__ int   cntSh, flagSh;

    // --- phase 1: zero ---
    scA[tid] = 0;
    if (tid == 0) flagSh = 0;
    __syncthreads();

    // --- phase 2: load + bucket count (2 items/thread, coalesced) ---
    u64 k0 = 0, k1 = 0; int bk0 = -1, bk1 = -1, r0 = 0, r1 = 0;
    if (tid < use) {
        k0 = gbase[tid];
        const u32 bits = (u32)(k0 >> 32);
        const u32 d = bits > BITS_BASE ? bits - BITS_BASE : 0u;
        bk0 = (NBUCK - 1) - (int)min(d >> 11, (u32)(NBUCK - 1));   // high score -> low bucket
        r0 = atomicAdd(&scA[bk0], 1);
    }
    if (tid + 1024 < use) {
        k1 = gbase[tid + 1024];
        const u32 bits = (u32)(k1 >> 32);
        const u32 d = bits > BITS_BASE ? bits - BITS_BASE : 0u;
        bk1 = (NBUCK - 1) - (int)min(d >> 11, (u32)(NBUCK - 1));
        r1 = atomicAdd(&scA[bk1], 1);
    }
    __syncthreads();

    // --- phase 3: exclusive prefix over buckets (Hillis-Steele, ping-pong) ---
    const int own = scA[tid];
    int* src = scA; int* dst = scB;
    for (int d = 1; d < NBUCK; d <<= 1) {
        int v = src[tid];
        if (tid >= d) v += src[tid - d];
        dst[tid] = v;
        __syncthreads();
        int* tmp = src; src = dst; dst = tmp;
    }
    dst[tid] = src[tid] - own;      // exclusive base (ends in scB: 10 swaps)
    __syncthreads();
    int* const bbase = dst;

    // --- phase 4: scatter + straddle-overflow check ---
    if (bk0 >= 0) { const int p = bbase[bk0] + r0; if (p < KEYS_MAX) keyS[p] = k0; }
    if (bk1 >= 0) { const int p = bbase[bk1] + r1; if (p < KEYS_MAX) keyS[p] = k1; }
    {
        const int bse = bbase[tid];
        if (own > 0 && bse < SCAN && bse + own > KEYS_MAX) flagSh = 1;
    }
    __syncthreads();

    // --- phase 5: per-bucket insertion sort (descending u64; ranks exact) ---
    {
        const int lo = bbase[tid];
        const int hi = min(lo + own, KEYS_MAX);
        if (own >= 2 && lo < KEYS_MAX) {
            for (int a = lo + 1; a < hi; ++a) {
                const u64 kk = keyS[a];
                int p = a - 1;
                while (p >= lo && keyS[p] < kk) { keyS[p + 1] = keyS[p]; --p; }
                keyS[p + 1] = kk;
            }
        }
    }
    __syncthreads();

    // --- phase 6: gather boxes SoA + areas ---
    if (tid < scanN) {
        const u64 kk = keyS[tid];
        const int n = (int)(0xFFFFFFFFu - (u32)kk);
        const float4 bx = *reinterpret_cast<const float4*>(boxb + (size_t)n * 4);
        sx1[tid] = bx.x; sy1[tid] = bx.y; sx2[tid] = bx.z; sy2[tid] = bx.w;
        sar[tid] = (bx.z - bx.x) * (bx.w - bx.y);
    }
    __syncthreads();

    // --- phase 7: upper-triangular mask (2304 words), wave-uniform early-out ---
    for (int t = wv; t < 2304; t += 16) {
        int i, w;
        if      (t <  512) { i = t >> 3;               w = t & 7; }
        else if (t <  960) { const int r = t -  512; i =  64 + r / 7;    w = 1 + r % 7; }
        else if (t < 1344) { const int r = t -  960; i = 128 + r / 6;    w = 2 + r % 6; }
        else if (t < 1664) { const int r = t - 1344; i = 192 + r / 5;    w = 3 + r % 5; }
        else if (t < 1920) { const int r = t - 1664; i = 256 + (r >> 2); w = 4 + (r & 3); }
        else if (t < 2112) { const int r = t - 1920; i = 320 + r / 3;    w = 5 + r % 3; }
        else if (t < 2240) { const int r = t - 2112; i = 384 + (r >> 1); w = 6 + (r & 1); }
        else               { i = 448 + (t - 2240);     w = 7; }
        const int j = w * 64 + ln;                     // j <= 511, safe LDS reads
        const bool iv = (i < scanN);
        const bool jv = (j < scanN) && (j != i);
        float px1 = 0.f, py1 = 0.f, px2 = 0.f, py2 = 0.f, pa = 0.f;
        if (iv) { px1 = sx1[i]; py1 = sy1[i]; px2 = sx2[i]; py2 = sy2[i]; pa = sar[i]; }
        const float qx1 = sx1[j], qy1 = sy1[j], qx2 = sx2[j], qy2 = sy2[j];
        const float ix1 = fmaxf(px1, qx1), iy1 = fmaxf(py1, qy1);
        const float ix2 = fminf(px2, qx2), iy2 = fminf(py2, qy2);
        const bool ov = iv && jv && (ix2 > ix1) && (iy2 > iy1);
        bool sup = false;
        if (__any(ov)) {
            const float inter = fmaxf(ix2 - ix1, 0.f) * fmaxf(iy2 - iy1, 0.f);
            const float aj = sar[j];
            const float iou = inter / (pa + aj - inter + 1e-8f);  // ref assoc order
            sup = ov && (iou > IOU_THR);
        }
        const u64 bal = __ballot(sup);
        if (ln == 0) mask[i][w] = bal;
    }
    __syncthreads();

    // --- phase 8: chunked greedy resolve (wave 0) ---
    if (wv == 0) {
        u64 remv[8] = {0, 0, 0, 0, 0, 0, 0, 0};
        int cnt = 0;
#pragma unroll
        for (int c = 0; c < 8; ++c) {                   // full unroll: static remv[c]
            if (cnt < MAXDET) {
                const int i = c * 64 + ln;
                const bool valid = (i < scanN);
                u64 alive = __ballot(valid && !((remv[c] >> ln) & 1ULL));
                const u64 sub = valid ? mask[i][c] : 0ULL;   // my column == my row (sym)
                u64 keptM = 0ULL;
                const int cbase = cnt;
                while (alive) {
                    const int f = __ffsll((unsigned long long)alive) - 1;
                    keptM |= (1ULL << f);
                    ++cnt;
                    if (cnt >= MAXDET) break;
                    const bool meSup = ((sub >> f) & 1ULL) != 0ULL;
                    const u64 supM = __ballot(meSup);
                    alive &= ~(supM | (1ULL << f));
                }
                if ((keptM >> ln) & 1ULL) {
                    const int pos = cbase + __popcll(keptM & ((1ULL << ln) - 1ULL));
                    const u64 kk = keyS[i];
                    ksc[pos] = __uint_as_float((u32)(kk >> 32));
                    kix[pos] = (int)(0xFFFFFFFFu - (u32)kk);
                }
                if (cnt < MAXDET && c < 7) {            // propagate removals forward
#pragma unroll
                    for (int w = 0; w < 8; ++w) {
                        if (w > c) {                    // only future-chunk words
                            u64 x = ((keptM >> ln) & 1ULL) ? mask[c * 64 + ln][w] : 0ULL;
#pragma unroll
                            for (int m = 1; m < 64; m <<= 1)
                                x |= (u64)__shfl_xor((long long)x, m);
                            remv[w] |= x;
                        }
                    }
                }
            }
        }
        if (ln == 0) cntSh = cnt;
    }
    __syncthreads();

    // --- phase 9: write out ---
    const int cnt = cntSh;
    for (int k2 = tid; k2 < cnt; k2 += 1024) {
        keptIdx[bc * MAXDET + k2]   = kix[k2];
        keptScore[bc * MAXDET + k2] = ksc[k2];
    }
    if (tid == 0) {
        keptCnt[bc] = cnt;
        flagInc[bc] = (raw > CAP
                       || flagSh
                       || (cnt < MAXDET && totalCand[bc] > use)   // pool cut by T0
                       || (cnt < MAXDET && use > scanN)           // window exhausted
                      ) ? 1 : 0;
    }
}

// ==================== slow path (round-1, verified) ====================

__device__ __forceinline__ void combineMax(float& bs, int& bi, float os, int oi) {
    if (os > bs || (os == bs && oi < bi)) { bs = os; bi = oi; }
}

template<int NPT>
__global__ __launch_bounds__(BS) void nms_slow_kernel(
    const float* __restrict__ boxes, const float* __restrict__ cls,
    const float* __restrict__ cent, int B, int N, int C,
    int* __restrict__ keptIdx, float* __restrict__ keptScore, int* __restrict__ keptCnt,
    const int* __restrict__ flagInc)
{
    const int bc = blockIdx.x;
    if (flagInc != nullptr && flagInc[bc] == 0) return;   // fast path was complete
    const int b   = bc / C;
    const int c   = bc - b * C;
    const int tid = threadIdx.x;

    const float* __restrict__ clsb  = cls  + (size_t)b * N * C + c;
    const float* __restrict__ centb = cent + (size_t)b * N;
    const float* __restrict__ boxb  = boxes + (size_t)b * N * 4;

    float s[NPT];
#pragma unroll
    for (int j = 0; j < NPT; ++j) {
        int n = tid + j * BS;
        float v = -1.0f;
        if (n < N) {
            float cv = clsb[(size_t)n * C];
            if (cv > SCORE_THR) v = sqrtf(cv * centb[n]);
        }
        s[j] = v;
    }

    __shared__ float kx1[MAXDET], ky1[MAXDET], kx2[MAXDET], ky2[MAXDET];
    __shared__ float kscore[MAXDET];
    __shared__ int   kidx[MAXDET];
    __shared__ float redS[BS / 64];
    __shared__ int   redI[BS / 64];
    __shared__ float pbox[4];
    __shared__ float pscoreSh;
    __shared__ int   ctrl;
    __shared__ int   supFlag;

    const int lane = tid & 63;
    const int wid  = tid >> 6;
    const int NW   = BS / 64;
    int cnt = 0;

    const int maxIter = N + MAXDET + 2;
    for (int iter = 0; iter < maxIter; ++iter) {
        float bs = -1.0f; int bi = 0x7fffffff;
#pragma unroll
        for (int j = 0; j < NPT; ++j) {
            if (s[j] > bs) { bs = s[j]; bi = tid + j * BS; }
        }
        for (int m = 1; m < 64; m <<= 1) {
            float os = __shfl_xor(bs, m);
            int   oi = __shfl_xor(bi, m);
            combineMax(bs, bi, os, oi);
        }
        if (lane == 0) { redS[wid] = bs; redI[wid] = bi; }
        __syncthreads();
        if (tid == 0) {
            float gs = redS[0]; int gi = redI[0];
            for (int w = 1; w < NW; ++w) combineMax(gs, gi, redS[w], redI[w]);
            supFlag = 0;
            if (gs <= 0.0f) {
                ctrl = -1;
            } else {
                ctrl = gi; pscoreSh = gs;
                const float4 bx = *reinterpret_cast<const float4*>(boxb + (size_t)gi * 4);
                pbox[0] = bx.x; pbox[1] = bx.y; pbox[2] = bx.z; pbox[3] = bx.w;
            }
        }
        __syncthreads();
        const int P = ctrl;
        if (P < 0) break;

        if ((P & (BS - 1)) == tid) {
            const int jp = P >> 10;
#pragma unroll
            for (int j = 0; j < NPT; ++j) if (j == jp) s[j] = -1.0f;
        }

        if (tid < cnt) {
            const float px1 = pbox[0], py1 = pbox[1], px2 = pbox[2], py2 = pbox[3];
            const float qx1 = kx1[tid], qy1 = ky1[tid], qx2 = kx2[tid], qy2 = ky2[tid];
            const float ix1 = fmaxf(qx1, px1), iy1 = fmaxf(qy1, py1);
            const float ix2 = fminf(qx2, px2), iy2 = fminf(qy2, py2);
            const float inter = fmaxf(ix2 - ix1, 0.0f) * fmaxf(iy2 - iy1, 0.0f);
            const float aq = (qx2 - qx1) * (qy2 - qy1);
            const float ap = (px2 - px1) * (py2 - py1);
            const float iou = inter / (aq + ap - inter + 1e-8f);
            if (iou > IOU_THR) supFlag = 1;
        }
        __syncthreads();
        if (supFlag == 0) {
            if (tid == 0) {
                kx1[cnt] = pbox[0]; ky1[cnt] = pbox[1];
                kx2[cnt] = pbox[2]; ky2[cnt] = pbox[3];
                kscore[cnt] = pscoreSh; kidx[cnt] = P;
            }
            ++cnt;
            if (cnt == MAXDET) break;
        }
    }

    for (int k = tid; k < cnt; k += BS) {
        keptIdx[(size_t)bc * MAXDET + k]   = kidx[k];
        keptScore[(size_t)bc * MAXDET + k] = kscore[k];
    }
    if (tid == 0) keptCnt[bc] = cnt;
}

// ==================== final top-300 (bitonic over 16x512) ====================

__global__ __launch_bounds__(1024) void topk_kernel(
    const float* __restrict__ boxes, const int* __restrict__ keptIdx,
    const float* __restrict__ keptScore, const int* __restrict__ keptCnt,
    int B, int N, int C, float* __restrict__ out)
{
    const int b   = blockIdx.x;
    const int tid = threadIdx.x;

    __shared__ u64 key[8192];
    __shared__ int cnts[16];
    if (tid < C) cnts[tid] = keptCnt[b * C + tid];
    __syncthreads();

    for (int i = tid; i < 8192; i += 1024) {
        const int c = i >> 9;          // 16 slots of 512 (cnt <= 300 < 512)
        const int k = i & 511;
        u64 v = ~0ULL;
        if (c < C && k < cnts[c]) {
            const float sc = keptScore[(b * C + c) * MAXDET + k];
            const int   fl = c * N + keptIdx[(b * C + c) * MAXDET + k];
            v = ~(((u64)__float_as_uint(sc) << 32) | (u32)(0xFFFFFFFFu - (u32)fl));
        }
        key[i] = v;
    }

    for (int k = 2; k <= 8192; k <<= 1) {
        for (int j = k >> 1; j > 0; j >>= 1) {
            __syncthreads();
            for (int i = tid; i < 8192; i += 1024) {
                const int l = i ^ j;
                if (l > i) {
                    const u64 a = key[i], bb = key[l];
                    const bool up = ((i & k) == 0);
                    if ((a > bb) == up) { key[i] = bb; key[l] = a; }
                }
            }
        }
    }
    __syncthreads();

    const int boff = b * MAXDET;
    for (int r = tid; r < MAXDET; r += 1024) {
        const u64 kk = ~key[r];
        const float sc = __uint_as_float((u32)(kk >> 32));
        float4 bx = make_float4(-1.0f, -1.0f, -1.0f, -1.0f);
        float so = -1.0f, lo = -1.0f;
        if (sc > 0.0f) {
            const int fl = (int)(0xFFFFFFFFu - (u32)kk);
            const int label  = fl / N;
            const int anchor = fl - label * N;
            bx = *reinterpret_cast<const float4*>(boxes + ((size_t)b * N + anchor) * 4);
            so = sc; lo = (float)label;
        }
        *reinterpret_cast<float4*>(out + (size_t)(boff + r) * 4) = bx;
        out[(size_t)B * MAXDET * 4 + boff + r] = so;
        out[(size_t)B * MAXDET * 5 + boff + r] = lo;
    }
}

// ============================ launcher ============================

extern "C" void kernel_launch(void* const* d_in, const int* in_sizes, int n_in,
                              void* d_out, int out_size, void* d_ws, size_t ws_size,
                              hipStream_t stream) {
    const float* boxes = (const float*)d_in[0];
    const float* cls   = (const float*)d_in[1];
    const float* cent  = (const float*)d_in[2];
    float* out = (float*)d_out;

    const int B = out_size / (MAXDET * 6);
    if (B <= 0) return;
    const int N = in_sizes[2] / B;
    const int C = in_sizes[1] / in_sizes[2];
    if (N <= 0 || C <= 0 || C > 16) return;
    const int BC = B * C;

    char* base = (char*)d_ws;
    size_t off = 0;
    int*   keptIdx   = (int*)(base + off);   off += (size_t)BC * MAXDET * sizeof(int);
    float* keptScore = (float*)(base + off); off += (size_t)BC * MAXDET * sizeof(float);
    int*   keptCnt   = (int*)(base + off);   off += (size_t)BC * sizeof(int);
    int*   flagInc   = (int*)(base + off);   off += (size_t)BC * sizeof(int);
    const size_t slowNeed = off;
    int*   cntRaw    = (int*)(base + off);   off += (size_t)BC * sizeof(int);
    int*   totalCand = (int*)(base + off);   off += (size_t)BC * sizeof(int);
    off = (off + 7) & ~(size_t)7;
    u64*   candPacked = (u64*)(base + off);  off += (size_t)BC * CAP * sizeof(u64);
    const size_t fastNeed = off;

    const int nptNeeded = (N + BS - 1) / BS;
    if (nptNeeded > 64) return;

    const bool fast = (C == 16) && (ws_size >= fastNeed);

    if (fast) {
        hipMemsetAsync(cntRaw, 0, 2 * (size_t)BC * sizeof(int), stream);
        score_compact_kernel<<<B * SPLIT, 256, 0, stream>>>(
            cls, cent, N, C, candPacked, cntRaw, totalCand);
        sort_nms_kernel<<<BC, 1024, 0, stream>>>(
            boxes, candPacked, cntRaw, totalCand, N, C,
            keptIdx, keptScore, keptCnt, flagInc);
        if (nptNeeded <= 49)
            nms_slow_kernel<49><<<BC, BS, 0, stream>>>(boxes, cls, cent, B, N, C,
                                                       keptIdx, keptScore, keptCnt, flagInc);
        else
            nms_slow_kernel<64><<<BC, BS, 0, stream>>>(boxes, cls, cent, B, N, C,
                                                       keptIdx, keptScore, keptCnt, flagInc);
    } else {
        if (ws_size < slowNeed) return;
        if (nptNeeded <= 49)
            nms_slow_kernel<49><<<BC, BS, 0, stream>>>(boxes, cls, cent, B, N, C,
                                                       keptIdx, keptScore, keptCnt, nullptr);
        else
            nms_slow_kernel<64><<<BC, BS, 0, stream>>>(boxes, cls, cent, B, N, C,
                                                       keptIdx, keptScore, keptCnt, nullptr);
    }

    topk_kernel<<<B, 1024, 0, stream>>>(boxes, keptIdx, keptScore, keptCnt, B, N, C, out);
}

// Round 7
// 172.809 us; speedup vs baseline: 7.4569x; 1.3288x over previous
//
#include <hip/hip_runtime.h>
#include <cstdint>
#include <cstddef>

#define MAXDET 300
#define IOU_THR 0.6f
#define SCORE_THR 0.05f
#define T0 0.9f          // combined-score compaction threshold (fallback-guarded)
#define CAP 2048         // per-class candidate capacity (expected ~1075)
#define SCAN 512         // NMS scan window over sorted candidates (examined ~345)
#define LCAP 64          // per-block per-class LDS list capacity in score pass
#define SPLIT 128        // blocks per image in score pass
#define BS 1024          // slow-path block size
#define NBUCK 1024       // bucket-sort bins
#define KEYS_MAX 576     // SCAN + slack for the straddling bucket
#define BITS_BASE 0x3F666666u   // float bits of 0.9f (fast-path scores >= 0.9)

typedef unsigned int u32;
typedef unsigned long long u64;

// ============================ fast path ============================

// Pass 1: coalesced score compute + LDS-aggregated per-class compaction.
__global__ __launch_bounds__(256) void score_compact_kernel(
    const float* __restrict__ cls, const float* __restrict__ cent,
    int N, int C,
    u64* __restrict__ candPacked, int* __restrict__ cntRaw, int* __restrict__ totalCand)
{
    const int b = blockIdx.x / SPLIT;
    const int s = blockIdx.x % SPLIT;
    const int chunk = (N + SPLIT - 1) / SPLIT;
    const int n0 = s * chunk;
    const int n1 = min(n0 + chunk, N);
    const int tid = threadIdx.x;
    const int q  = tid & 3;        // quarter-row: classes 4q..4q+3
    const int ar = tid >> 2;       // anchor offset within 64-anchor tile

    __shared__ int lcnt[16];
    __shared__ int ltot[16];
    __shared__ int lbase[16];
    __shared__ u64 lbuf[16][LCAP];

    if (tid < 16) { lcnt[tid] = 0; ltot[tid] = 0; }
    __syncthreads();

    int myTot[4] = {0, 0, 0, 0};
    for (int n = n0 + ar; n < n1; n += 64) {
        const float4 r = *reinterpret_cast<const float4*>(
            cls + ((size_t)b * N + n) * 16 + q * 4);
        const float ce = cent[(size_t)b * N + n];
        const float cv[4] = {r.x, r.y, r.z, r.w};
#pragma unroll
        for (int u = 0; u < 4; ++u) {
            const float v = cv[u];
            if (v > SCORE_THR) {
                myTot[u]++;
                const float prod = v * ce;
                if (prod >= 0.80f) {                       // conservative pre-filter
                    const float comb = sqrtf(prod);        // exact ref expression
                    if (comb >= T0) {
                        const int c = 4 * q + u;
                        const u64 key = ((u64)__float_as_uint(comb) << 32)
                                      | (u32)(0xFFFFFFFFu - (u32)n);  // score desc, n asc
                        const int lp = atomicAdd(&lcnt[c], 1);
                        if (lp < LCAP) {
                            lbuf[c][lp] = key;
                        } else {  // overflow (astronomically rare): direct append
                            const int pos = atomicAdd(&cntRaw[b * 16 + c], 1);
                            if (pos < CAP)
                                candPacked[((size_t)(b * 16 + c) << 11) + pos] = key;
                        }
                    }
                }
            }
        }
    }
#pragma unroll
    for (int u = 0; u < 4; ++u) atomicAdd(&ltot[4 * q + u], myTot[u]);
    __syncthreads();

    if (tid < 16) {
        const int m = min(lcnt[tid], LCAP);
        lbase[tid] = atomicAdd(&cntRaw[b * 16 + tid], m);   // reserve range
        atomicAdd(&totalCand[b * 16 + tid], ltot[tid]);
    }
    __syncthreads();

    for (int idx = tid; idx < 16 * LCAP; idx += 256) {      // coalesced flush
        const int c = idx >> 6;            // LCAP == 64
        const int k = idx & 63;
        if (k < min(lcnt[c], LCAP)) {
            const int pos = lbase[c] + k;
            if (pos < CAP)
                candPacked[((size_t)(b * 16 + c) << 11) + pos] = lbuf[c][k];
        }
    }
}

// Pass 2 (fused bucket-sort + mask + chunked NMS), one 1024-thread block per (b,c).
// (unchanged from round 6 -- verified absmax 0.0; will be profiled next round)
__global__ __launch_bounds__(1024) void sort_nms_kernel(
    const float* __restrict__ boxes, const u64* __restrict__ candPacked,
    const int* __restrict__ cntRaw, const int* __restrict__ totalCand,
    int N, int C,
    int* __restrict__ keptIdx, float* __restrict__ keptScore,
    int* __restrict__ keptCnt, int* __restrict__ flagInc)
{
    const int bc  = blockIdx.x;
    const int b   = bc / C;
    const int tid = threadIdx.x;
    const int wv  = tid >> 6;
    const int ln  = tid & 63;
    const int raw = cntRaw[bc];
    const int use = min(raw, CAP);
    const int scanN = min(use, SCAN);
    const float* __restrict__ boxb = boxes + (size_t)b * N * 4;
    const u64* __restrict__ gbase = candPacked + ((size_t)bc << 11);

    __shared__ u64   keyS[KEYS_MAX];                       // 4.5 KB sorted keys
    __shared__ float sx1[SCAN], sy1[SCAN], sx2[SCAN], sy2[SCAN], sar[SCAN]; // 10 KB
    __shared__ int   scA[NBUCK];                           // 4 KB
    __shared__ int   scB[NBUCK];                           // 4 KB
    __shared__ u64   mask[SCAN][9];                        // 36 KB (pad 9 vs 8)
    __shared__ float ksc[MAXDET];
    __shared__ int   kix[MAXDET];
    __shared__ int   cntSh, flagSh;

    // --- phase 1: zero ---
    scA[tid] = 0;
    if (tid == 0) flagSh = 0;
    __syncthreads();

    // --- phase 2: load + bucket count (2 items/thread, coalesced) ---
    u64 k0 = 0, k1 = 0; int bk0 = -1, bk1 = -1, r0 = 0, r1 = 0;
    if (tid < use) {
        k0 = gbase[tid];
        const u32 bits = (u32)(k0 >> 32);
        const u32 d = bits > BITS_BASE ? bits - BITS_BASE : 0u;
        bk0 = (NBUCK - 1) - (int)min(d >> 11, (u32)(NBUCK - 1));   // high score -> low bucket
        r0 = atomicAdd(&scA[bk0], 1);
    }
    if (tid + 1024 < use) {
        k1 = gbase[tid + 1024];
        const u32 bits = (u32)(k1 >> 32);
        const u32 d = bits > BITS_BASE ? bits - BITS_BASE : 0u;
        bk1 = (NBUCK - 1) - (int)min(d >> 11, (u32)(NBUCK - 1));
        r1 = atomicAdd(&scA[bk1], 1);
    }
    __syncthreads();

    // --- phase 3: exclusive prefix over buckets (Hillis-Steele, ping-pong) ---
    const int own = scA[tid];
    int* src = scA; int* dst = scB;
    for (int d = 1; d < NBUCK; d <<= 1) {
        int v = src[tid];
        if (tid >= d) v += src[tid - d];
        dst[tid] = v;
        __syncthreads();
        int* tmp = src; src = dst; dst = tmp;
    }
    dst[tid] = src[tid] - own;      // exclusive base (ends in scB: 10 swaps)
    __syncthreads();
    int* const bbase = dst;

    // --- phase 4: scatter + straddle-overflow check ---
    if (bk0 >= 0) { const int p = bbase[bk0] + r0; if (p < KEYS_MAX) keyS[p] = k0; }
    if (bk1 >= 0) { const int p = bbase[bk1] + r1; if (p < KEYS_MAX) keyS[p] = k1; }
    {
        const int bse = bbase[tid];
        if (own > 0 && bse < SCAN && bse + own > KEYS_MAX) flagSh = 1;
    }
    __syncthreads();

    // --- phase 5: per-bucket insertion sort (descending u64; ranks exact) ---
    {
        const int lo = bbase[tid];
        const int hi = min(lo + own, KEYS_MAX);
        if (own >= 2 && lo < KEYS_MAX) {
            for (int a = lo + 1; a < hi; ++a) {
                const u64 kk = keyS[a];
                int p = a - 1;
                while (p >= lo && keyS[p] < kk) { keyS[p + 1] = keyS[p]; --p; }
                keyS[p + 1] = kk;
            }
        }
    }
    __syncthreads();

    // --- phase 6: gather boxes SoA + areas ---
    if (tid < scanN) {
        const u64 kk = keyS[tid];
        const int n = (int)(0xFFFFFFFFu - (u32)kk);
        const float4 bx = *reinterpret_cast<const float4*>(boxb + (size_t)n * 4);
        sx1[tid] = bx.x; sy1[tid] = bx.y; sx2[tid] = bx.z; sy2[tid] = bx.w;
        sar[tid] = (bx.z - bx.x) * (bx.w - bx.y);
    }
    __syncthreads();

    // --- phase 7: upper-triangular mask (2304 words), wave-uniform early-out ---
    for (int t = wv; t < 2304; t += 16) {
        int i, w;
        if      (t <  512) { i = t >> 3;               w = t & 7; }
        else if (t <  960) { const int r = t -  512; i =  64 + r / 7;    w = 1 + r % 7; }
        else if (t < 1344) { const int r = t -  960; i = 128 + r / 6;    w = 2 + r % 6; }
        else if (t < 1664) { const int r = t - 1344; i = 192 + r / 5;    w = 3 + r % 5; }
        else if (t < 1920) { const int r = t - 1664; i = 256 + (r >> 2); w = 4 + (r & 3); }
        else if (t < 2112) { const int r = t - 1920; i = 320 + r / 3;    w = 5 + r % 3; }
        else if (t < 2240) { const int r = t - 2112; i = 384 + (r >> 1); w = 6 + (r & 1); }
        else               { i = 448 + (t - 2240);     w = 7; }
        const int j = w * 64 + ln;                     // j <= 511, safe LDS reads
        const bool iv = (i < scanN);
        const bool jv = (j < scanN) && (j != i);
        float px1 = 0.f, py1 = 0.f, px2 = 0.f, py2 = 0.f, pa = 0.f;
        if (iv) { px1 = sx1[i]; py1 = sy1[i]; px2 = sx2[i]; py2 = sy2[i]; pa = sar[i]; }
        const float qx1 = sx1[j], qy1 = sy1[j], qx2 = sx2[j], qy2 = sy2[j];
        const float ix1 = fmaxf(px1, qx1), iy1 = fmaxf(py1, qy1);
        const float ix2 = fminf(px2, qx2), iy2 = fminf(py2, qy2);
        const bool ov = iv && jv && (ix2 > ix1) && (iy2 > iy1);
        bool sup = false;
        if (__any(ov)) {
            const float inter = fmaxf(ix2 - ix1, 0.f) * fmaxf(iy2 - iy1, 0.f);
            const float aj = sar[j];
            const float iou = inter / (pa + aj - inter + 1e-8f);  // ref assoc order
            sup = ov && (iou > IOU_THR);
        }
        const u64 bal = __ballot(sup);
        if (ln == 0) mask[i][w] = bal;
    }
    __syncthreads();

    // --- phase 8: chunked greedy resolve (wave 0) ---
    if (wv == 0) {
        u64 remv[8] = {0, 0, 0, 0, 0, 0, 0, 0};
        int cnt = 0;
#pragma unroll
        for (int c = 0; c < 8; ++c) {                   // full unroll: static remv[c]
            if (cnt < MAXDET) {
                const int i = c * 64 + ln;
                const bool valid = (i < scanN);
                u64 alive = __ballot(valid && !((remv[c] >> ln) & 1ULL));
                const u64 sub = valid ? mask[i][c] : 0ULL;   // my column == my row (sym)
                u64 keptM = 0ULL;
                const int cbase = cnt;
                while (alive) {
                    const int f = __ffsll((unsigned long long)alive) - 1;
                    keptM |= (1ULL << f);
                    ++cnt;
                    if (cnt >= MAXDET) break;
                    const bool meSup = ((sub >> f) & 1ULL) != 0ULL;
                    const u64 supM = __ballot(meSup);
                    alive &= ~(supM | (1ULL << f));
                }
                if ((keptM >> ln) & 1ULL) {
                    const int pos = cbase + __popcll(keptM & ((1ULL << ln) - 1ULL));
                    const u64 kk = keyS[i];
                    ksc[pos] = __uint_as_float((u32)(kk >> 32));
                    kix[pos] = (int)(0xFFFFFFFFu - (u32)kk);
                }
                if (cnt < MAXDET && c < 7) {            // propagate removals forward
#pragma unroll
                    for (int w = 0; w < 8; ++w) {
                        if (w > c) {                    // only future-chunk words
                            u64 x = ((keptM >> ln) & 1ULL) ? mask[c * 64 + ln][w] : 0ULL;
#pragma unroll
                            for (int m = 1; m < 64; m <<= 1)
                                x |= (u64)__shfl_xor((long long)x, m);
                            remv[w] |= x;
                        }
                    }
                }
            }
        }
        if (ln == 0) cntSh = cnt;
    }
    __syncthreads();

    // --- phase 9: write out ---
    const int cnt = cntSh;
    for (int k2 = tid; k2 < cnt; k2 += 1024) {
        keptIdx[bc * MAXDET + k2]   = kix[k2];
        keptScore[bc * MAXDET + k2] = ksc[k2];
    }
    if (tid == 0) {
        keptCnt[bc] = cnt;
        flagInc[bc] = (raw > CAP
                       || flagSh
                       || (cnt < MAXDET && totalCand[bc] > use)   // pool cut by T0
                       || (cnt < MAXDET && use > scanN)           // window exhausted
                      ) ? 1 : 0;
    }
}

// ==================== slow path (round-1, verified) ====================

__device__ __forceinline__ void combineMax(float& bs, int& bi, float os, int oi) {
    if (os > bs || (os == bs && oi < bi)) { bs = os; bi = oi; }
}

template<int NPT>
__global__ __launch_bounds__(BS) void nms_slow_kernel(
    const float* __restrict__ boxes, const float* __restrict__ cls,
    const float* __restrict__ cent, int B, int N, int C,
    int* __restrict__ keptIdx, float* __restrict__ keptScore, int* __restrict__ keptCnt,
    const int* __restrict__ flagInc)
{
    const int bc = blockIdx.x;
    if (flagInc != nullptr && flagInc[bc] == 0) return;   // fast path was complete
    const int b   = bc / C;
    const int c   = bc - b * C;
    const int tid = threadIdx.x;

    const float* __restrict__ clsb  = cls  + (size_t)b * N * C + c;
    const float* __restrict__ centb = cent + (size_t)b * N;
    const float* __restrict__ boxb  = boxes + (size_t)b * N * 4;

    float s[NPT];
#pragma unroll
    for (int j = 0; j < NPT; ++j) {
        int n = tid + j * BS;
        float v = -1.0f;
        if (n < N) {
            float cv = clsb[(size_t)n * C];
            if (cv > SCORE_THR) v = sqrtf(cv * centb[n]);
        }
        s[j] = v;
    }

    __shared__ float kx1[MAXDET], ky1[MAXDET], kx2[MAXDET], ky2[MAXDET];
    __shared__ float kscore[MAXDET];
    __shared__ int   kidx[MAXDET];
    __shared__ float redS[BS / 64];
    __shared__ int   redI[BS / 64];
    __shared__ float pbox[4];
    __shared__ float pscoreSh;
    __shared__ int   ctrl;
    __shared__ int   supFlag;

    const int lane = tid & 63;
    const int wid  = tid >> 6;
    const int NW   = BS / 64;
    int cnt = 0;

    const int maxIter = N + MAXDET + 2;
    for (int iter = 0; iter < maxIter; ++iter) {
        float bs = -1.0f; int bi = 0x7fffffff;
#pragma unroll
        for (int j = 0; j < NPT; ++j) {
            if (s[j] > bs) { bs = s[j]; bi = tid + j * BS; }
        }
        for (int m = 1; m < 64; m <<= 1) {
            float os = __shfl_xor(bs, m);
            int   oi = __shfl_xor(bi, m);
            combineMax(bs, bi, os, oi);
        }
        if (lane == 0) { redS[wid] = bs; redI[wid] = bi; }
        __syncthreads();
        if (tid == 0) {
            float gs = redS[0]; int gi = redI[0];
            for (int w = 1; w < NW; ++w) combineMax(gs, gi, redS[w], redI[w]);
            supFlag = 0;
            if (gs <= 0.0f) {
                ctrl = -1;
            } else {
                ctrl = gi; pscoreSh = gs;
                const float4 bx = *reinterpret_cast<const float4*>(boxb + (size_t)gi * 4);
                pbox[0] = bx.x; pbox[1] = bx.y; pbox[2] = bx.z; pbox[3] = bx.w;
            }
        }
        __syncthreads();
        const int P = ctrl;
        if (P < 0) break;

        if ((P & (BS - 1)) == tid) {
            const int jp = P >> 10;
#pragma unroll
            for (int j = 0; j < NPT; ++j) if (j == jp) s[j] = -1.0f;
        }

        if (tid < cnt) {
            const float px1 = pbox[0], py1 = pbox[1], px2 = pbox[2], py2 = pbox[3];
            const float qx1 = kx1[tid], qy1 = ky1[tid], qx2 = kx2[tid], qy2 = ky2[tid];
            const float ix1 = fmaxf(qx1, px1), iy1 = fmaxf(qy1, py1);
            const float ix2 = fminf(qx2, px2), iy2 = fminf(qy2, py2);
            const float inter = fmaxf(ix2 - ix1, 0.0f) * fmaxf(iy2 - iy1, 0.0f);
            const float aq = (qx2 - qx1) * (qy2 - qy1);
            const float ap = (px2 - px1) * (py2 - py1);
            const float iou = inter / (aq + ap - inter + 1e-8f);
            if (iou > IOU_THR) supFlag = 1;
        }
        __syncthreads();
        if (supFlag == 0) {
            if (tid == 0) {
                kx1[cnt] = pbox[0]; ky1[cnt] = pbox[1];
                kx2[cnt] = pbox[2]; ky2[cnt] = pbox[3];
                kscore[cnt] = pscoreSh; kidx[cnt] = P;
            }
            ++cnt;
            if (cnt == MAXDET) break;
        }
    }

    for (int k = tid; k < cnt; k += BS) {
        keptIdx[(size_t)bc * MAXDET + k]   = kidx[k];
        keptScore[(size_t)bc * MAXDET + k] = kscore[k];
    }
    if (tid == 0) keptCnt[bc] = cnt;
}

// ========== final top-300: bucket sort of C*300 kept keys (1 block/image) ==========
// Replaces the 91-pass bitonic-8192 (107 us at 8-block occupancy). Same proven
// machinery as sort_nms phases 1-5: bucket count -> Hillis-Steele scan ->
// scatter -> per-bucket insertion sort -> array globally descending. Keys pack
// (score_bits, ~flat) so order + tie-breaks are bit-identical to the bitonic.
__global__ __launch_bounds__(1024) void topk_kernel(
    const float* __restrict__ boxes, const int* __restrict__ keptIdx,
    const float* __restrict__ keptScore, const int* __restrict__ keptCnt,
    int B, int N, int C, float* __restrict__ out)
{
    const int b   = blockIdx.x;
    const int tid = threadIdx.x;

    __shared__ int cnts[16];
    __shared__ int cntA[NBUCK];
    __shared__ int cntB[NBUCK];
    __shared__ u64 sorted[16 * MAXDET];     // 37.5 KB
    __shared__ int totalSh;

    if (tid < 16) cnts[tid] = (tid < C) ? keptCnt[b * C + tid] : 0;
    cntA[tid] = 0;
    __syncthreads();
    if (tid == 0) {
        int t = 0;
        for (int c = 0; c < C; ++c) t += cnts[c];
        totalSh = t;
    }

    // load + bucket count (5 items/thread max: 16*300/1024 = 4.69)
    const int TOT = C * MAXDET;
    u64 mk[5]; int mb[5], mr[5];
#pragma unroll
    for (int t = 0; t < 5; ++t) {
        mb[t] = -1;
        const int i = tid + t * 1024;
        if (i < TOT) {
            const int c = i / MAXDET;
            const int k = i - c * MAXDET;
            if (k < cnts[c]) {
                const float sc = keptScore[(b * C + c) * MAXDET + k];
                const u32 fl = (u32)(c * N + keptIdx[(b * C + c) * MAXDET + k]);
                const u64 kk = ((u64)__float_as_uint(sc) << 32) | (0xFFFFFFFFu - fl);
                const u32 bits = (u32)(kk >> 32);
                const u32 d = bits > BITS_BASE ? bits - BITS_BASE : 0u;
                const int bk = (NBUCK - 1) - (int)min(d >> 11, (u32)(NBUCK - 1));
                mk[t] = kk; mb[t] = bk; mr[t] = atomicAdd(&cntA[bk], 1);
            }
        }
    }
    __syncthreads();

    // exclusive prefix over buckets (identical ping-pong to sort_nms phase 3)
    const int own = cntA[tid];
    int* src = cntA; int* dst = cntB;
    for (int d = 1; d < NBUCK; d <<= 1) {
        int v = src[tid];
        if (tid >= d) v += src[tid - d];
        dst[tid] = v;
        __syncthreads();
        int* tmp = src; src = dst; dst = tmp;
    }
    dst[tid] = src[tid] - own;
    __syncthreads();
    int* const bb = dst;

    // scatter
#pragma unroll
    for (int t = 0; t < 5; ++t)
        if (mb[t] >= 0) sorted[bb[mb[t]] + mr[t]] = mk[t];
    __syncthreads();

    // per-bucket insertion sort (descending)
    {
        const int lo = bb[tid];
        const int hi = lo + own;
        if (own >= 2) {
            for (int a = lo + 1; a < hi; ++a) {
                const u64 kk = sorted[a];
                int p = a - 1;
                while (p >= lo && sorted[p] < kk) { sorted[p + 1] = sorted[p]; --p; }
                sorted[p + 1] = kk;
            }
        }
    }
    __syncthreads();

    // write top-300 directly
    const int total = totalSh;
    if (tid < MAXDET) {
        float4 bx = make_float4(-1.0f, -1.0f, -1.0f, -1.0f);
        float so = -1.0f, lo2 = -1.0f;
        if (tid < total) {
            const u64 kk = sorted[tid];
            so = __uint_as_float((u32)(kk >> 32));
            const int fl = (int)(0xFFFFFFFFu - (u32)kk);
            const int label  = fl / N;
            const int anchor = fl - label * N;
            bx = *reinterpret_cast<const float4*>(boxes + ((size_t)b * N + anchor) * 4);
            lo2 = (float)label;
        }
        *reinterpret_cast<float4*>(out + (size_t)(b * MAXDET + tid) * 4) = bx;
        out[(size_t)B * MAXDET * 4 + b * MAXDET + tid] = so;
        out[(size_t)B * MAXDET * 5 + b * MAXDET + tid] = lo2;
    }
}

// ============================ launcher ============================

extern "C" void kernel_launch(void* const* d_in, const int* in_sizes, int n_in,
                              void* d_out, int out_size, void* d_ws, size_t ws_size,
                              hipStream_t stream) {
    const float* boxes = (const float*)d_in[0];
    const float* cls   = (const float*)d_in[1];
    const float* cent  = (const float*)d_in[2];
    float* out = (float*)d_out;

    const int B = out_size / (MAXDET * 6);
    if (B <= 0) return;
    const int N = in_sizes[2] / B;
    const int C = in_sizes[1] / in_sizes[2];
    if (N <= 0 || C <= 0 || C > 16) return;
    const int BC = B * C;

    char* base = (char*)d_ws;
    size_t off = 0;
    int*   keptIdx   = (int*)(base + off);   off += (size_t)BC * MAXDET * sizeof(int);
    float* keptScore = (float*)(base + off); off += (size_t)BC * MAXDET * sizeof(float);
    int*   keptCnt   = (int*)(base + off);   off += (size_t)BC * sizeof(int);
    int*   flagInc   = (int*)(base + off);   off += (size_t)BC * sizeof(int);
    const size_t slowNeed = off;
    int*   cntRaw    = (int*)(base + off);   off += (size_t)BC * sizeof(int);
    int*   totalCand = (int*)(base + off);   off += (size_t)BC * sizeof(int);
    off = (off + 7) & ~(size_t)7;
    u64*   candPacked = (u64*)(base + off);  off += (size_t)BC * CAP * sizeof(u64);
    const size_t fastNeed = off;

    const int nptNeeded = (N + BS - 1) / BS;
    if (nptNeeded > 64) return;

    const bool fast = (C == 16) && (ws_size >= fastNeed);

    if (fast) {
        hipMemsetAsync(cntRaw, 0, 2 * (size_t)BC * sizeof(int), stream);
        score_compact_kernel<<<B * SPLIT, 256, 0, stream>>>(
            cls, cent, N, C, candPacked, cntRaw, totalCand);
        sort_nms_kernel<<<BC, 1024, 0, stream>>>(
            boxes, candPacked, cntRaw, totalCand, N, C,
            keptIdx, keptScore, keptCnt, flagInc);
        if (nptNeeded <= 49)
            nms_slow_kernel<49><<<BC, BS, 0, stream>>>(boxes, cls, cent, B, N, C,
                                                       keptIdx, keptScore, keptCnt, flagInc);
        else
            nms_slow_kernel<64><<<BC, BS, 0, stream>>>(boxes, cls, cent, B, N, C,
                                                       keptIdx, keptScore, keptCnt, flagInc);
    } else {
        if (ws_size < slowNeed) return;
        if (nptNeeded <= 49)
            nms_slow_kernel<49><<<BC, BS, 0, stream>>>(boxes, cls, cent, B, N, C,
                                                       keptIdx, keptScore, keptCnt, nullptr);
        else
            nms_slow_kernel<64><<<BC, BS, 0, stream>>>(boxes, cls, cent, B, N, C,
                                                       keptIdx, keptScore, keptCnt, nullptr);
    }

    topk_kernel<<<B, 1024, 0, stream>>>(boxes, keptIdx, keptScore, keptCnt, B, N, C, out);
}

// Round 9
// 133.875 us; speedup vs baseline: 9.6255x; 1.2908x over previous
//
#include <hip/hip_runtime.h>
#include <cstdint>
#include <cstddef>

#define MAXDET 300
#define IOU_THR 0.6f
#define SCORE_THR 0.05f
#define T0 0.9f          // combined-score compaction threshold (fallback-guarded)
#define CAP 2048         // per-class candidate capacity (expected ~1075)
#define SCAN 512         // NMS scan window over sorted candidates (examined ~345)
#define LCAP 64          // per-block per-class LDS list capacity in score pass
#define SPLIT 128        // blocks per image in score pass
#define BS 1024          // slow-path block size
#define NBUCK 1024       // bucket-sort bins
#define KEYS_MAX 576     // SCAN + slack for the straddling bucket
#define BITS_BASE 0x3F666666u   // float bits of 0.9f (fast-path scores >= 0.9)

typedef unsigned int u32;
typedef unsigned long long u64;

// ============================ fast path ============================

// Pass 1: coalesced score compute + LDS-aggregated per-class compaction.
__global__ __launch_bounds__(256) void score_compact_kernel(
    const float* __restrict__ cls, const float* __restrict__ cent,
    int N, int C,
    u64* __restrict__ candPacked, int* __restrict__ cntRaw, int* __restrict__ totalCand)
{
    const int b = blockIdx.x / SPLIT;
    const int s = blockIdx.x % SPLIT;
    const int chunk = (N + SPLIT - 1) / SPLIT;
    const int n0 = s * chunk;
    const int n1 = min(n0 + chunk, N);
    const int tid = threadIdx.x;
    const int q  = tid & 3;        // quarter-row: classes 4q..4q+3
    const int ar = tid >> 2;       // anchor offset within 64-anchor tile

    __shared__ int lcnt[16];
    __shared__ int ltot[16];
    __shared__ int lbase[16];
    __shared__ u64 lbuf[16][LCAP];

    if (tid < 16) { lcnt[tid] = 0; ltot[tid] = 0; }
    __syncthreads();

    int myTot[4] = {0, 0, 0, 0};
    for (int n = n0 + ar; n < n1; n += 64) {
        const float4 r = *reinterpret_cast<const float4*>(
            cls + ((size_t)b * N + n) * 16 + q * 4);
        const float ce = cent[(size_t)b * N + n];
        const float cv[4] = {r.x, r.y, r.z, r.w};
#pragma unroll
        for (int u = 0; u < 4; ++u) {
            const float v = cv[u];
            if (v > SCORE_THR) {
                myTot[u]++;
                const float prod = v * ce;
                if (prod >= 0.80f) {                       // conservative pre-filter
                    const float comb = sqrtf(prod);        // exact ref expression
                    if (comb >= T0) {
                        const int c = 4 * q + u;
                        const u64 key = ((u64)__float_as_uint(comb) << 32)
                                      | (u32)(0xFFFFFFFFu - (u32)n);  // score desc, n asc
                        const int lp = atomicAdd(&lcnt[c], 1);
                        if (lp < LCAP) {
                            lbuf[c][lp] = key;
                        } else {  // overflow (astronomically rare): direct append
                            const int pos = atomicAdd(&cntRaw[b * 16 + c], 1);
                            if (pos < CAP)
                                candPacked[((size_t)(b * 16 + c) << 11) + pos] = key;
                        }
                    }
                }
            }
        }
    }
#pragma unroll
    for (int u = 0; u < 4; ++u) atomicAdd(&ltot[4 * q + u], myTot[u]);
    __syncthreads();

    if (tid < 16) {
        const int m = min(lcnt[tid], LCAP);
        lbase[tid] = atomicAdd(&cntRaw[b * 16 + tid], m);   // reserve range
        atomicAdd(&totalCand[b * 16 + tid], ltot[tid]);
    }
    __syncthreads();

    for (int idx = tid; idx < 16 * LCAP; idx += 256) {      // coalesced flush
        const int c = idx >> 6;            // LCAP == 64
        const int k = idx & 63;
        if (k < min(lcnt[c], LCAP)) {
            const int pos = lbase[c] + k;
            if (pos < CAP)
                candPacked[((size_t)(b * 16 + c) << 11) + pos] = lbuf[c][k];
        }
    }
}

// Pass 2 (fused bucket-sort + mask + chunked NMS), one 1024-thread block per (b,c).
// Phase 7 register-caches the j-boxes (each lane only ever needs j = w*64+ln,
// w<8 -> 40 VGPRs loaded from LDS once per wave), row-outer loop with 5
// broadcast reads per row. LDS-pipe ops in the mask phase drop ~25k -> ~5.5k
// wave-ops (the round-7 104us was LDS-throughput-bound). IoU arithmetic
// bit-identical: same expression, operand roles, j-ranges.
__global__ __launch_bounds__(1024) void sort_nms_kernel(
    const float* __restrict__ boxes, const u64* __restrict__ candPacked,
    const int* __restrict__ cntRaw, const int* __restrict__ totalCand,
    int N, int C,
    int* __restrict__ keptIdx, float* __restrict__ keptScore,
    int* __restrict__ keptCnt, int* __restrict__ flagInc)
{
    const int bc  = blockIdx.x;
    const int b   = bc / C;
    const int tid = threadIdx.x;
    const int wv  = tid >> 6;
    const int ln  = tid & 63;
    const int raw = cntRaw[bc];
    const int use = min(raw, CAP);
    const int scanN = min(use, SCAN);
    const float* __restrict__ boxb = boxes + (size_t)b * N * 4;
    const u64* __restrict__ gbase = candPacked + ((size_t)bc << 11);

    __shared__ u64   keyS[KEYS_MAX];                       // 4.5 KB sorted keys
    __shared__ float sx1[SCAN], sy1[SCAN], sx2[SCAN], sy2[SCAN], sar[SCAN]; // 10 KB
    __shared__ int   scA[NBUCK];                           // 4 KB
    __shared__ int   scB[NBUCK];                           // 4 KB
    __shared__ u64   mask[SCAN][9];                        // 36 KB (pad 9 vs 8)
    __shared__ float ksc[MAXDET];
    __shared__ int   kix[MAXDET];
    __shared__ int   cntSh, flagSh;

    // --- phase 1: zero ---
    scA[tid] = 0;
    if (tid == 0) flagSh = 0;
    __syncthreads();

    // --- phase 2: load + bucket count (2 items/thread, coalesced) ---
    u64 k0 = 0, k1 = 0; int bk0 = -1, bk1 = -1, r0 = 0, r1 = 0;
    if (tid < use) {
        k0 = gbase[tid];
        const u32 bits = (u32)(k0 >> 32);
        const u32 d = bits > BITS_BASE ? bits - BITS_BASE : 0u;
        bk0 = (NBUCK - 1) - (int)min(d >> 11, (u32)(NBUCK - 1));   // high score -> low bucket
        r0 = atomicAdd(&scA[bk0], 1);
    }
    if (tid + 1024 < use) {
        k1 = gbase[tid + 1024];
        const u32 bits = (u32)(k1 >> 32);
        const u32 d = bits > BITS_BASE ? bits - BITS_BASE : 0u;
        bk1 = (NBUCK - 1) - (int)min(d >> 11, (u32)(NBUCK - 1));
        r1 = atomicAdd(&scA[bk1], 1);
    }
    __syncthreads();

    // --- phase 3: exclusive prefix over buckets (Hillis-Steele, ping-pong) ---
    const int own = scA[tid];
    int* src = scA; int* dst = scB;
    for (int d = 1; d < NBUCK; d <<= 1) {
        int v = src[tid];
        if (tid >= d) v += src[tid - d];
        dst[tid] = v;
        __syncthreads();
        int* tmp = src; src = dst; dst = tmp;
    }
    dst[tid] = src[tid] - own;      // exclusive base (ends in scB: 10 swaps)
    __syncthreads();
    int* const bbase = dst;

    // --- phase 4: scatter + straddle-overflow check ---
    if (bk0 >= 0) { const int p = bbase[bk0] + r0; if (p < KEYS_MAX) keyS[p] = k0; }
    if (bk1 >= 0) { const int p = bbase[bk1] + r1; if (p < KEYS_MAX) keyS[p] = k1; }
    {
        const int bse = bbase[tid];
        if (own > 0 && bse < SCAN && bse + own > KEYS_MAX) flagSh = 1;
    }
    __syncthreads();

    // --- phase 5: per-bucket insertion sort (descending u64; ranks exact) ---
    {
        const int lo = bbase[tid];
        const int hi = min(lo + own, KEYS_MAX);
        if (own >= 2 && lo < KEYS_MAX) {
            for (int a = lo + 1; a < hi; ++a) {
                const u64 kk = keyS[a];
                int p = a - 1;
                while (p >= lo && keyS[p] < kk) { keyS[p + 1] = keyS[p]; --p; }
                keyS[p + 1] = kk;
            }
        }
    }
    __syncthreads();

    // --- phase 6: gather boxes SoA + areas ---
    if (tid < scanN) {
        const u64 kk = keyS[tid];
        const int n = (int)(0xFFFFFFFFu - (u32)kk);
        const float4 bx = *reinterpret_cast<const float4*>(boxb + (size_t)n * 4);
        sx1[tid] = bx.x; sy1[tid] = bx.y; sx2[tid] = bx.z; sy2[tid] = bx.w;
        sar[tid] = (bx.z - bx.x) * (bx.w - bx.y);
    }
    __syncthreads();

    // --- phase 7: mask build, register-cached j-boxes, row-outer ---
    {
        // per-lane j-box cache: j = w*64 + ln (static indices only)
        float rjx1[8], rjy1[8], rjx2[8], rjy2[8], rja[8];
#pragma unroll
        for (int w = 0; w < 8; ++w) {
            const int j = w * 64 + ln;
            rjx1[w] = sx1[j]; rjy1[w] = sy1[j];
            rjx2[w] = sx2[j]; rjy2[w] = sy2[j];
            rja[w]  = sar[j];
        }
        for (int i = wv; i < scanN; i += 16) {
            const float px1 = sx1[i], py1 = sy1[i];      // LDS broadcasts
            const float px2 = sx2[i], py2 = sy2[i];
            const float pa  = sar[i];
            const int wlo = i >> 6;                      // diagonal word
#pragma unroll
            for (int w = 0; w < 8; ++w) {
                if (w >= wlo) {                          // wave-uniform skip (upper tri)
                    const int j = w * 64 + ln;
                    const bool jv = (j < scanN) && (j != i);
                    const float ix1 = fmaxf(px1, rjx1[w]), iy1 = fmaxf(py1, rjy1[w]);
                    const float ix2 = fminf(px2, rjx2[w]), iy2 = fminf(py2, rjy2[w]);
                    const bool ov = jv && (ix2 > ix1) && (iy2 > iy1);
                    bool sup = false;
                    if (__any(ov)) {
                        const float inter = fmaxf(ix2 - ix1, 0.f) * fmaxf(iy2 - iy1, 0.f);
                        const float iou = inter / (pa + rja[w] - inter + 1e-8f); // ref order
                        sup = ov && (iou > IOU_THR);
                    }
                    const u64 bal = __ballot(sup);
                    if (ln == 0) mask[i][w] = bal;
                }
            }
        }
    }
    __syncthreads();

    // --- phase 8: chunked greedy resolve (wave 0) ---
    if (wv == 0) {
        u64 remv[8] = {0, 0, 0, 0, 0, 0, 0, 0};
        int cnt = 0;
#pragma unroll
        for (int c = 0; c < 8; ++c) {                   // full unroll: static remv[c]
            if (cnt < MAXDET) {
                const int i = c * 64 + ln;
                const bool valid = (i < scanN);
                u64 alive = __ballot(valid && !((remv[c] >> ln) & 1ULL));
                const u64 sub = valid ? mask[i][c] : 0ULL;   // my column == my row (sym)
                u64 keptM = 0ULL;
                const int cbase = cnt;
                while (alive) {
                    const int f = __ffsll((unsigned long long)alive) - 1;
                    keptM |= (1ULL << f);
                    ++cnt;
                    if (cnt >= MAXDET) break;
                    const bool meSup = ((sub >> f) & 1ULL) != 0ULL;
                    const u64 supM = __ballot(meSup);
                    alive &= ~(supM | (1ULL << f));
                }
                if ((keptM >> ln) & 1ULL) {
                    const int pos = cbase + __popcll(keptM & ((1ULL << ln) - 1ULL));
                    const u64 kk = keyS[i];
                    ksc[pos] = __uint_as_float((u32)(kk >> 32));
                    kix[pos] = (int)(0xFFFFFFFFu - (u32)kk);
                }
                if (cnt < MAXDET && c < 7) {            // propagate removals forward
#pragma unroll
                    for (int w = 0; w < 8; ++w) {
                        if (w > c) {                    // only future-chunk words
                            u64 x = ((keptM >> ln) & 1ULL) ? mask[c * 64 + ln][w] : 0ULL;
#pragma unroll
                            for (int m = 1; m < 64; m <<= 1)
                                x |= (u64)__shfl_xor((long long)x, m);
                            remv[w] |= x;
                        }
                    }
                }
            }
        }
        if (ln == 0) cntSh = cnt;
    }
    __syncthreads();

    // --- phase 9: write out ---
    const int cnt = cntSh;
    for (int k2 = tid; k2 < cnt; k2 += 1024) {
        keptIdx[bc * MAXDET + k2]   = kix[k2];
        keptScore[bc * MAXDET + k2] = ksc[k2];
    }
    if (tid == 0) {
        keptCnt[bc] = cnt;
        flagInc[bc] = (raw > CAP
                       || flagSh
                       || (cnt < MAXDET && totalCand[bc] > use)   // pool cut by T0
                       || (cnt < MAXDET && use > scanN)           // window exhausted
                      ) ? 1 : 0;
    }
}

// ==================== slow path (round-1, verified) ====================

__device__ __forceinline__ void combineMax(float& bs, int& bi, float os, int oi) {
    if (os > bs || (os == bs && oi < bi)) { bs = os; bi = oi; }
}

template<int NPT>
__global__ __launch_bounds__(BS) void nms_slow_kernel(
    const float* __restrict__ boxes, const float* __restrict__ cls,
    const float* __restrict__ cent, int B, int N, int C,
    int* __restrict__ keptIdx, float* __restrict__ keptScore, int* __restrict__ keptCnt,
    const int* __restrict__ flagInc)
{
    const int bc = blockIdx.x;
    if (flagInc != nullptr && flagInc[bc] == 0) return;   // fast path was complete
    const int b   = bc / C;
    const int c   = bc - b * C;
    const int tid = threadIdx.x;

    const float* __restrict__ clsb  = cls  + (size_t)b * N * C + c;
    const float* __restrict__ centb = cent + (size_t)b * N;
    const float* __restrict__ boxb  = boxes + (size_t)b * N * 4;

    float s[NPT];
#pragma unroll
    for (int j = 0; j < NPT; ++j) {
        int n = tid + j * BS;
        float v = -1.0f;
        if (n < N) {
            float cv = clsb[(size_t)n * C];
            if (cv > SCORE_THR) v = sqrtf(cv * centb[n]);
        }
        s[j] = v;
    }

    __shared__ float kx1[MAXDET], ky1[MAXDET], kx2[MAXDET], ky2[MAXDET];
    __shared__ float kscore[MAXDET];
    __shared__ int   kidx[MAXDET];
    __shared__ float redS[BS / 64];
    __shared__ int   redI[BS / 64];
    __shared__ float pbox[4];
    __shared__ float pscoreSh;
    __shared__ int   ctrl;
    __shared__ int   supFlag;

    const int lane = tid & 63;
    const int wid  = tid >> 6;
    const int NW   = BS / 64;
    int cnt = 0;

    const int maxIter = N + MAXDET + 2;
    for (int iter = 0; iter < maxIter; ++iter) {
        float bs = -1.0f; int bi = 0x7fffffff;
#pragma unroll
        for (int j = 0; j < NPT; ++j) {
            if (s[j] > bs) { bs = s[j]; bi = tid + j * BS; }
        }
        for (int m = 1; m < 64; m <<= 1) {
            float os = __shfl_xor(bs, m);
            int   oi = __shfl_xor(bi, m);
            combineMax(bs, bi, os, oi);
        }
        if (lane == 0) { redS[wid] = bs; redI[wid] = bi; }
        __syncthreads();
        if (tid == 0) {
            float gs = redS[0]; int gi = redI[0];
            for (int w = 1; w < NW; ++w) combineMax(gs, gi, redS[w], redI[w]);
            supFlag = 0;
            if (gs <= 0.0f) {
                ctrl = -1;
            } else {
                ctrl = gi; pscoreSh = gs;
                const float4 bx = *reinterpret_cast<const float4*>(boxb + (size_t)gi * 4);
                pbox[0] = bx.x; pbox[1] = bx.y; pbox[2] = bx.z; pbox[3] = bx.w;
            }
        }
        __syncthreads();
        const int P = ctrl;
        if (P < 0) break;

        if ((P & (BS - 1)) == tid) {
            const int jp = P >> 10;
#pragma unroll
            for (int j = 0; j < NPT; ++j) if (j == jp) s[j] = -1.0f;
        }

        if (tid < cnt) {
            const float px1 = pbox[0], py1 = pbox[1], px2 = pbox[2], py2 = pbox[3];
            const float qx1 = kx1[tid], qy1 = ky1[tid], qx2 = kx2[tid], qy2 = ky2[tid];
            const float ix1 = fmaxf(qx1, px1), iy1 = fmaxf(qy1, py1);
            const float ix2 = fminf(qx2, px2), iy2 = fminf(qy2, py2);
            const float inter = fmaxf(ix2 - ix1, 0.0f) * fmaxf(iy2 - iy1, 0.0f);
            const float aq = (qx2 - qx1) * (qy2 - qy1);
            const float ap = (px2 - px1) * (py2 - py1);
            const float iou = inter / (aq + ap - inter + 1e-8f);
            if (iou > IOU_THR) supFlag = 1;
        }
        __syncthreads();
        if (supFlag == 0) {
            if (tid == 0) {
                kx1[cnt] = pbox[0]; ky1[cnt] = pbox[1];
                kx2[cnt] = pbox[2]; ky2[cnt] = pbox[3];
                kscore[cnt] = pscoreSh; kidx[cnt] = P;
            }
            ++cnt;
            if (cnt == MAXDET) break;
        }
    }

    for (int k = tid; k < cnt; k += BS) {
        keptIdx[(size_t)bc * MAXDET + k]   = kidx[k];
        keptScore[(size_t)bc * MAXDET + k] = kscore[k];
    }
    if (tid == 0) keptCnt[bc] = cnt;
}

// ========== final top-300: bucket sort of C*300 kept keys (1 block/image) ==========
__global__ __launch_bounds__(1024) void topk_kernel(
    const float* __restrict__ boxes, const int* __restrict__ keptIdx,
    const float* __restrict__ keptScore, const int* __restrict__ keptCnt,
    int B, int N, int C, float* __restrict__ out)
{
    const int b   = blockIdx.x;
    const int tid = threadIdx.x;

    __shared__ int cnts[16];
    __shared__ int cntA[NBUCK];
    __shared__ int cntB[NBUCK];
    __shared__ u64 sorted[16 * MAXDET];     // 37.5 KB
    __shared__ int totalSh;

    if (tid < 16) cnts[tid] = (tid < C) ? keptCnt[b * C + tid] : 0;
    cntA[tid] = 0;
    __syncthreads();
    if (tid == 0) {
        int t = 0;
        for (int c = 0; c < C; ++c) t += cnts[c];
        totalSh = t;
    }

    // load + bucket count (5 items/thread max: 16*300/1024 = 4.69)
    const int TOT = C * MAXDET;
    u64 mk[5]; int mb[5], mr[5];
#pragma unroll
    for (int t = 0; t < 5; ++t) {
        mb[t] = -1;
        const int i = tid + t * 1024;
        if (i < TOT) {
            const int c = i / MAXDET;
            const int k = i - c * MAXDET;
            if (k < cnts[c]) {
                const float sc = keptScore[(b * C + c) * MAXDET + k];
                const u32 fl = (u32)(c * N + keptIdx[(b * C + c) * MAXDET + k]);
                const u64 kk = ((u64)__float_as_uint(sc) << 32) | (0xFFFFFFFFu - fl);
                const u32 bits = (u32)(kk >> 32);
                const u32 d = bits > BITS_BASE ? bits - BITS_BASE : 0u;
                const int bk = (NBUCK - 1) - (int)min(d >> 11, (u32)(NBUCK - 1));
                mk[t] = kk; mb[t] = bk; mr[t] = atomicAdd(&cntA[bk], 1);
            }
        }
    }
    __syncthreads();

    // exclusive prefix over buckets
    const int own = cntA[tid];
    int* src = cntA; int* dst = cntB;
    for (int d = 1; d < NBUCK; d <<= 1) {
        int v = src[tid];
        if (tid >= d) v += src[tid - d];
        dst[tid] = v;
        __syncthreads();
        int* tmp = src; src = dst; dst = tmp;
    }
    dst[tid] = src[tid] - own;
    __syncthreads();
    int* const bb = dst;

    // scatter
#pragma unroll
    for (int t = 0; t < 5; ++t)
        if (mb[t] >= 0) sorted[bb[mb[t]] + mr[t]] = mk[t];
    __syncthreads();

    // per-bucket insertion sort (descending)
    {
        const int lo = bb[tid];
        const int hi = lo + own;
        if (own >= 2) {
            for (int a = lo + 1; a < hi; ++a) {
                const u64 kk = sorted[a];
                int p = a - 1;
                while (p >= lo && sorted[p] < kk) { sorted[p + 1] = sorted[p]; --p; }
                sorted[p + 1] = kk;
            }
        }
    }
    __syncthreads();

    // write top-300 directly
    const int total = totalSh;
    if (tid < MAXDET) {
        float4 bx = make_float4(-1.0f, -1.0f, -1.0f, -1.0f);
        float so = -1.0f, lo2 = -1.0f;
        if (tid < total) {
            const u64 kk = sorted[tid];
            so = __uint_as_float((u32)(kk >> 32));
            const int fl = (int)(0xFFFFFFFFu - (u32)kk);
            const int label  = fl / N;
            const int anchor = fl - label * N;
            bx = *reinterpret_cast<const float4*>(boxes + ((size_t)b * N + anchor) * 4);
            lo2 = (float)label;
        }
        *reinterpret_cast<float4*>(out + (size_t)(b * MAXDET + tid) * 4) = bx;
        out[(size_t)B * MAXDET * 4 + b * MAXDET + tid] = so;
        out[(size_t)B * MAXDET * 5 + b * MAXDET + tid] = lo2;
    }
}

// ============================ launcher ============================

extern "C" void kernel_launch(void* const* d_in, const int* in_sizes, int n_in,
                              void* d_out, int out_size, void* d_ws, size_t ws_size,
                              hipStream_t stream) {
    const float* boxes = (const float*)d_in[0];
    const float* cls   = (const float*)d_in[1];
    const float* cent  = (const float*)d_in[2];
    float* out = (float*)d_out;

    const int B = out_size / (MAXDET * 6);
    if (B <= 0) return;
    const int N = in_sizes[2] / B;
    const int C = in_sizes[1] / in_sizes[2];
    if (N <= 0 || C <= 0 || C > 16) return;
    const int BC = B * C;

    char* base = (char*)d_ws;
    size_t off = 0;
    int*   keptIdx   = (int*)(base + off);   off += (size_t)BC * MAXDET * sizeof(int);
    float* keptScore = (float*)(base + off); off += (size_t)BC * MAXDET * sizeof(float);
    int*   keptCnt   = (int*)(base + off);   off += (size_t)BC * sizeof(int);
    int*   flagInc   = (int*)(base + off);   off += (size_t)BC * sizeof(int);
    const size_t slowNeed = off;
    int*   cntRaw    = (int*)(base + off);   off += (size_t)BC * sizeof(int);
    int*   totalCand = (int*)(base + off);   off += (size_t)BC * sizeof(int);
    off = (off + 7) & ~(size_t)7;
    u64*   candPacked = (u64*)(base + off);  off += (size_t)BC * CAP * sizeof(u64);
    const size_t fastNeed = off;

    const int nptNeeded = (N + BS - 1) / BS;
    if (nptNeeded > 64) return;

    const bool fast = (C == 16) && (ws_size >= fastNeed);

    if (fast) {
        hipMemsetAsync(cntRaw, 0, 2 * (size_t)BC * sizeof(int), stream);
        score_compact_kernel<<<B * SPLIT, 256, 0, stream>>>(
            cls, cent, N, C, candPacked, cntRaw, totalCand);
        sort_nms_kernel<<<BC, 1024, 0, stream>>>(
            boxes, candPacked, cntRaw, totalCand, N, C,
            keptIdx, keptScore, keptCnt, flagInc);
        if (nptNeeded <= 49)
            nms_slow_kernel<49><<<BC, BS, 0, stream>>>(boxes, cls, cent, B, N, C,
                                                       keptIdx, keptScore, keptCnt, flagInc);
        else
            nms_slow_kernel<64><<<BC, BS, 0, stream>>>(boxes, cls, cent, B, N, C,
                                                       keptIdx, keptScore, keptCnt, flagInc);
    } else {
        if (ws_size < slowNeed) return;
        if (nptNeeded <= 49)
            nms_slow_kernel<49><<<BC, BS, 0, stream>>>(boxes, cls, cent, B, N, C,
                                                       keptIdx, keptScore, keptCnt, nullptr);
        else
            nms_slow_kernel<64><<<BC, BS, 0, stream>>>(boxes, cls, cent, B, N, C,
                                                       keptIdx, keptScore, keptCnt, nullptr);
    }

    topk_kernel<<<B, 1024, 0, stream>>>(boxes, keptIdx, keptScore, keptCnt, B, N, C, out);
}